// Round 11
// baseline (969.162 us; speedup 1.0000x reference)
//
#include <hip/hip_runtime.h>
#include <hip/hip_bf16.h>

#define DEVI __device__ __forceinline__

typedef short bf16x8 __attribute__((ext_vector_type(8)));
typedef float f32x4  __attribute__((ext_vector_type(4)));

static constexpr int Bb   = 128;
static constexpr int Ss   = 512;
static constexpr int Hh   = 1024;
static constexpr int Ee   = 512;
static constexpr int Vv   = 50257;
static constexpr int TWOH = 2048;

DEVI short f2bf(float f){ __hip_bfloat16 h = __float2bfloat16(f); return *reinterpret_cast<short*>(&h); }
DEVI float bf2f(short s){ __hip_bfloat16 h = *reinterpret_cast<__hip_bfloat16*>(&s); return __bfloat162float(h); }

DEVI float tanh_fast(float x){            // 1 - 2/(e^2x + 1): ±inf-safe, ~1e-7 rel err
  float e = __expf(2.0f*x);
  return 1.0f - 2.0f/(e + 1.0f);
}

DEVI bf16x8 pack8(f32x4 a, f32x4 b){
  bf16x8 v;
  v[0]=f2bf(a[0]); v[1]=f2bf(a[1]); v[2]=f2bf(a[2]); v[3]=f2bf(a[3]);
  v[4]=f2bf(b[0]); v[5]=f2bf(b[1]); v[6]=f2bf(b[2]); v[7]=f2bf(b[3]);
  return v;
}

DEVI void gld_lds16(const void* g, void* l){
  __builtin_amdgcn_global_load_lds((const __attribute__((address_space(1))) void*)g,
                                   (__attribute__((address_space(3))) void*)l, 16, 0, 0);
}

DEVI f32x4 mfma16(bf16x8 a, bf16x8 b, f32x4 c){
  return __builtin_amdgcn_mfma_f32_16x16x32_bf16(a, b, c, 0, 0, 0);
}

// ---------------- prep: convert W_ae->bf16, h->bf16, gather emb into x_bf16 ----------------
__global__ void k_prep(const float* __restrict__ wae, short* __restrict__ waeb,
                       const float* __restrict__ h, short* __restrict__ hb,
                       const int* __restrict__ dec_in, const float* __restrict__ emb,
                       short* __restrict__ xb)
{
  const int total_wae = Hh*TWOH;
  const int total_h   = Bb*Hh;
  const int total_emb = Bb*Ee;
  const int total = total_wae + total_h + total_emb;
  for (int i = blockIdx.x*blockDim.x + threadIdx.x; i < total; i += gridDim.x*blockDim.x){
    if (i < total_wae) waeb[i] = f2bf(wae[i]);
    else if (i < total_wae + total_h){ int j = i - total_wae; hb[j] = f2bf(h[j]); }
    else {
      int j = i - total_wae - total_h;
      int b = j >> 9, e = j & 511;
      xb[b*2560 + e] = f2bf(emb[(size_t)dec_in[b]*Ee + e]);
    }
  }
}

// ---------------- scores GEMM, FUSED fp32->bf16 conversion, DISTANCE-2 A pipeline ------
// 256x256 tile, 8 waves (2M x 4N), BK=64, A+B double-buffered (128KB LDS).
// A read fp32 from enc via a 2-deep register pipeline (paA/paB, rule-#20-safe
// 2-tile unroll): PREFA(t+2) issued in half2 of tile t, committed (pack8 +
// ds_write_b128) in half2 of tile t+1 -> a full K-tile (~1400cyc) of latency
// cover. nb==0 blocks also persist converted regs to encb for k_ctx.
// Tile boundary: counted vmcnt(8) (= PREFA(t+2)'s loads stay in flight,
// retires STB(t+1)+STOREE which are older) + lgkmcnt(0) + s_barrier.
// XCD grouping: q&7 = XCD; 4 consecutive same-XCD blocks share one fp32 A
// panel (2MB) in that XCD's L2 (r10-measured: FETCH 328MB vs 541 separate).
__launch_bounds__(512)
__global__ void k_scores_fuse(const float* __restrict__ enc, short* __restrict__ encb,
                              const short* __restrict__ waeb,
                              const float* __restrict__ ahb, const float* __restrict__ b_ah,
                              const float* __restrict__ b_ae, const float* __restrict__ wsc,
                              float* __restrict__ scores)
{
  __shared__ __align__(16) char LDSB[131072];   // A: 2x32KB @0, B: 2x32KB @65536
  const int q  = blockIdx.x;
  const int xcd = q & 7, sl = q >> 3;
  const int rt = xcd*32 + (sl>>2), nb = sl & 3; // rt 0..255, nb 0..3 (bijective)
  const int tid = threadIdx.x, wid = tid>>6, lane = tid&63;
  const int wr = wid>>2, wc = wid&3;            // 2M x 4N waves
  const int srow = lane>>3, l7 = lane&7;
  const int lo = lane&15, hi4 = lane>>4;
  const int swk = (l7 ^ srow)*8;                // pre-swizzled source k-chunk (elems)

  const float* Ag = enc  + (size_t)rt*256*TWOH + (size_t)(wid*8+srow)*TWOH + swk;
  const short* Bg = waeb + (size_t)nb*256*TWOH + (size_t)(wid*8+srow)*TWOH + swk;
  short*       Eg = encb + (size_t)rt*256*TWOH + (size_t)(wid*8+srow)*TWOH + swk;
  const bool we = (nb == 0) && (encb != nullptr);

  char* AWc = LDSB + wid*1024 + lane*16;        // + buf*32768 + rnd*8192 (ds_write)
  char* BW  = LDSB + 65536 + wid*1024;          // + buf*32768 + rnd*8192 (gld_lds, lane implicit)
  const char* AR = LDSB + (wr*128 + lo)*128;    // + buf*32768 + i*2048 + sw
  const char* BR = LDSB + 65536 + (wc*64 + lo)*128;
  const int sw0 = (hi4*16) ^ (l7<<4);           // kk=0 swizzled byte offset
  const int sw1 = (64 + hi4*16) ^ (l7<<4);      // kk=1

  f32x4 acc[8][4] = {};
  f32x4 paA[4][2], paB[4][2];                   // two pending A reg sets (distance-2)

  auto STB = [&](int buf, int kt){
    #pragma unroll
    for (int rnd=0; rnd<4; ++rnd)
      gld_lds16(Bg + (size_t)rnd*64*TWOH + kt*64, BW + buf*32768 + rnd*8192);
  };
  auto PREFA = [&](int kt, f32x4 (&pa)[4][2]){
    #pragma unroll
    for (int rnd=0; rnd<4; ++rnd){
      const float* p = Ag + (size_t)rnd*64*TWOH + kt*64;
      pa[rnd][0] = *(const f32x4*)p; pa[rnd][1] = *(const f32x4*)(p+4);
    }
  };
  auto COMMITA = [&](int buf, f32x4 (&pa)[4][2]){
    #pragma unroll
    for (int rnd=0; rnd<4; ++rnd)
      *(bf16x8*)(AWc + buf*32768 + rnd*8192) = pack8(pa[rnd][0], pa[rnd][1]);
  };
  auto STOREE = [&](int kt, f32x4 (&pa)[4][2]){
    #pragma unroll
    for (int rnd=0; rnd<4; ++rnd)
      *(bf16x8*)(Eg + (size_t)rnd*64*TWOH + kt*64) = pack8(pa[rnd][0], pa[rnd][1]);
  };

  // prologue: stage tile 0, prefetch A(1); counted wait keeps PREFA(1) in flight
  PREFA(0, paA); STB(0,0); COMMITA(0, paA);
  if (we) STOREE(0, paA);
  PREFA(1, paA);
  asm volatile("s_waitcnt vmcnt(8)" ::: "memory");   // retires STB(0)(+stores)
  asm volatile("s_waitcnt lgkmcnt(0)" ::: "memory");
  __builtin_amdgcn_s_barrier();
  __builtin_amdgcn_sched_barrier(0);

  auto TILE = [&](int t, f32x4 (&paC)[4][2], f32x4 (&paN)[4][2]){
    const int cur = t&1, nxt = cur^1;
    const int aO = cur*32768, bO = cur*32768;
    bf16x8 af[4], bq[4];

    // ---- half 1 (kk0): issue B(t+1) gld_lds (pinned); 32 MFMA ----
    if (t<31) STB(nxt, t+1);
    __builtin_amdgcn_sched_barrier(0);               // pin STB before later vmem
    #pragma unroll
    for (int j=0;j<4;++j) bq[j] = *(const bf16x8*)(BR + bO + j*2048 + sw0);
    #pragma unroll
    for (int i=0;i<4;++i) af[i] = *(const bf16x8*)(AR + aO + i*2048 + sw0);
    __builtin_amdgcn_s_setprio(1);
    #pragma unroll
    for (int i=0;i<4;++i)
      #pragma unroll
      for (int j=0;j<4;++j)
        acc[i][j] = mfma16(af[i], bq[j], acc[i][j]);
    __builtin_amdgcn_s_setprio(0);
    #pragma unroll
    for (int i=0;i<4;++i) af[i] = *(const bf16x8*)(AR + aO + (4+i)*2048 + sw0);
    __builtin_amdgcn_s_setprio(1);
    #pragma unroll
    for (int i=0;i<4;++i)
      #pragma unroll
      for (int j=0;j<4;++j)
        acc[4+i][j] = mfma16(af[i], bq[j], acc[4+i][j]);
    __builtin_amdgcn_s_setprio(0);

    // ---- half 2 (kk1): commit A(t+1) (loaded a full tile ago), store encb,
    //      issue PREFA(t+2); 32 MFMA ----
    if (t<31){
      COMMITA(nxt, paC);
      if (we) STOREE(t+1, paC);
    }
    if (t<30) PREFA(t+2, paN);
    #pragma unroll
    for (int j=0;j<4;++j) bq[j] = *(const bf16x8*)(BR + bO + j*2048 + sw1);
    #pragma unroll
    for (int i=0;i<4;++i) af[i] = *(const bf16x8*)(AR + aO + i*2048 + sw1);
    __builtin_amdgcn_s_setprio(1);
    #pragma unroll
    for (int i=0;i<4;++i)
      #pragma unroll
      for (int j=0;j<4;++j)
        acc[i][j] = mfma16(af[i], bq[j], acc[i][j]);
    __builtin_amdgcn_s_setprio(0);
    #pragma unroll
    for (int i=0;i<4;++i) af[i] = *(const bf16x8*)(AR + aO + (4+i)*2048 + sw1);
    __builtin_amdgcn_s_setprio(1);
    #pragma unroll
    for (int i=0;i<4;++i)
      #pragma unroll
      for (int j=0;j<4;++j)
        acc[4+i][j] = mfma16(af[i], bq[j], acc[4+i][j]);
    __builtin_amdgcn_s_setprio(0);

    if (t<30)       asm volatile("s_waitcnt vmcnt(8)" ::: "memory"); // PREFA(t+2) stays in flight
    else if (t==30) asm volatile("s_waitcnt vmcnt(0)" ::: "memory"); // tail drain
    if (t<31){
      asm volatile("s_waitcnt lgkmcnt(0)" ::: "memory");
      __builtin_amdgcn_s_barrier();
      __builtin_amdgcn_sched_barrier(0);
    }
  };

  #pragma unroll 1
  for (int tt = 0; tt < 16; ++tt){
    TILE(2*tt,   paA, paB);
    TILE(2*tt+1, paB, paA);
  }

  // epilogue: scores[m] += sum_n tanh(ah[b,n]+b_ah+b_ae+ae)*w_score[n]
  const int b = rt >> 1;                        // 256-row tile = half a batch row
  float w4[4], t4[4];
  #pragma unroll
  for (int j=0;j<4;++j){
    int n = nb*256 + wc*64 + j*16 + lo;
    w4[j] = wsc[n];
    t4[j] = ahb[b*Hh + n] + b_ah[n] + b_ae[n];
  }
  #pragma unroll
  for (int i=0;i<8;++i){
    #pragma unroll
    for (int q2=0;q2<4;++q2){
      int m = rt*256 + wr*128 + i*16 + hi4*4 + q2;
      float s = 0.f;
      #pragma unroll
      for (int j=0;j<4;++j) s += tanh_fast(t4[j] + acc[i][j][q2]) * w4[j];
      s += __shfl_xor(s,1); s += __shfl_xor(s,2); s += __shfl_xor(s,4); s += __shfl_xor(s,8);
      if (lo == 0) atomicAdd(&scores[m], s);
    }
  }
}

// ---------------- generic 128-row GEMM: A[128,K] bf16 ws, B[N,K] fp32 global --------------
template<int MODE>
__launch_bounds__(256)
__global__ void k_gemm128(const short* __restrict__ A, int lda,
                          const float* __restrict__ B0, const float* __restrict__ B1,
                          float* __restrict__ O0, float* __restrict__ O1,
                          const float* __restrict__ bias, int kiters)
{
  __shared__ __align__(16) short As[2][128*64];
  __shared__ __align__(16) short Bs[2][128*64];
  const int nb = blockIdx.x;
  const int tid = threadIdx.x, wid = tid>>6, lane = tid&63;
  const int wr = wid>>1, wc = wid&1;
  const int srow = lane>>3, l7 = lane&7;
  const int swk = (l7 ^ srow) * 8;

  const float* Bt; int noff; float* Ot; int ostride;
  if constexpr (MODE==0){
    if (nb < 8){ Bt = B0; noff = 0;    Ot = O0; ostride = Hh;   }
    else       { Bt = B1; noff = 1024; Ot = O1; ostride = 3*Hh; }
  } else if constexpr (MODE==1){ Bt = B0; noff = 0; Ot = O0; ostride = 3*Hh; }
  else { Bt = B0; noff = 0; Ot = O0; ostride = Vv; }

  f32x4 acc[4][4] = {};
  f32x4 pb0[4], pb1[4];

  auto stageA = [&](int s, int kt){
    #pragma unroll
    for (int i=0;i<4;++i){
      int c = wid*4+i, row = c*8+srow;
      gld_lds16(A + (size_t)row*lda + kt*64 + swk, (char*)As[s] + c*1024);
    }
  };
  auto prefB = [&](int kt){
    #pragma unroll
    for (int i=0;i<4;++i){
      int row = (wid*4+i)*8+srow;
      int n = nb*128 + row - noff;
      if constexpr (MODE==2) n = (n > Vv-1) ? (Vv-1) : n;
      const float* bp = Bt + (size_t)n*lda + kt*64 + l7*8;
      pb0[i] = *(const f32x4*)bp; pb1[i] = *(const f32x4*)(bp+4);
    }
  };
  auto commitB = [&](int s){
    #pragma unroll
    for (int i=0;i<4;++i){
      int row = (wid*4+i)*8+srow;
      *(bf16x8*)((char*)Bs[s] + row*128 + ((l7^srow)<<4)) = pack8(pb0[i], pb1[i]);
    }
  };

  const int kt0 = blockIdx.y * kiters, kend = kt0 + kiters;
  stageA(0, kt0); prefB(kt0); commitB(0);
  __syncthreads();

  int cur = 0;
  for (int kt = kt0; kt < kend; ++kt){
    if (kt+1 < kend){ stageA(cur^1, kt+1); prefB(kt+1); }
    #pragma unroll
    for (int kk=0;kk<2;++kk){
      bf16x8 af[4], bq[4];
      const int sw = (kk*64 + (lane>>4)*16) ^ (l7<<4);
      #pragma unroll
      for (int i=0;i<4;++i) af[i] = *(const bf16x8*)((const char*)As[cur] + (wr*64+i*16+(lane&15))*128 + sw);
      #pragma unroll
      for (int j=0;j<4;++j) bq[j] = *(const bf16x8*)((const char*)Bs[cur] + (wc*64+j*16+(lane&15))*128 + sw);
      #pragma unroll
      for (int i=0;i<4;++i)
        #pragma unroll
        for (int j=0;j<4;++j)
          acc[i][j] = mfma16(af[i], bq[j], acc[i][j]);
    }
    if (kt+1 < kend) commitB(cur^1);
    __syncthreads();
    cur ^= 1;
  }
  const int lo = lane&15, hi = lane>>4;
  #pragma unroll
  for (int i=0;i<4;++i){
    #pragma unroll
    for (int j=0;j<4;++j){
      int n = nb*128 + wc*64 + j*16 + lo - noff;
      #pragma unroll
      for (int q=0;q<4;++q){
        int m = wr*64 + i*16 + hi*4 + q;
        float v = acc[i][j][q];
        if constexpr (MODE==2){
          if (n < Vv) O0[(size_t)m*Vv + n] = v + bias[n];
        } else {
          atomicAdd(&Ot[(size_t)m*ostride + n], v);
        }
      }
    }
  }
}

// ---------------- softmax over S=512 per batch row ----------------
__global__ void k_softmax(const float* __restrict__ scores, float* __restrict__ attn)
{
  __shared__ float red[512];
  const int b = blockIdx.x, tid = threadIdx.x;
  float v = scores[b*Ss + tid];
  red[tid] = v; __syncthreads();
  for (int off=256; off>0; off>>=1){ if (tid<off) red[tid] = fmaxf(red[tid], red[tid+off]); __syncthreads(); }
  float mx = red[0]; __syncthreads();
  float e = __expf(v - mx);
  red[tid] = e; __syncthreads();
  for (int off=256; off>0; off>>=1){ if (tid<off) red[tid] += red[tid+off]; __syncthreads(); }
  attn[b*Ss + tid] = e / red[0];
}

// ---------------- ctx partial: bf16 enc, 4 row-chunks of 128, vectorized ----------------
__global__ void k_ctx_bf16(const short* __restrict__ encb, const float* __restrict__ attn,
                           float* __restrict__ ctxp)
{
  __shared__ float a[128];
  const int bid = blockIdx.x, b = bid>>2, ch = bid&3, tid = threadIdx.x;
  if (tid < 128) a[tid] = attn[b*Ss + ch*128 + tid];
  __syncthreads();
  const short* e0 = encb + (size_t)(b*Ss + ch*128)*TWOH + tid*8;
  float s[8] = {};
  for (int r=0; r<128; ++r){
    bf16x8 v = *(const bf16x8*)(e0 + (size_t)r*TWOH);
    float w = a[r];
    #pragma unroll
    for (int j=0;j<8;++j) s[j] += w * bf2f(v[j]);
  }
  float* o = ctxp + (size_t)ch*Bb*TWOH + (size_t)b*TWOH + tid*8;
  #pragma unroll
  for (int j=0;j<8;++j) o[j] = s[j];
}

__global__ void k_ctxfin(const float* __restrict__ ctxp, short* __restrict__ xb)
{
  const int g = blockIdx.x*256 + threadIdx.x;
  const int b = g >> 11, col = g & 2047;
  const int N = Bb*TWOH;
  float v = ctxp[g] + ctxp[N+g] + ctxp[2*N+g] + ctxp[3*N+g];
  xb[b*2560 + 512 + col] = f2bf(v);
}

// fallback (small ws): fp32 enc, writes xb directly
__global__ void k_ctx_f32(const float* __restrict__ enc, const float* __restrict__ attn,
                          short* __restrict__ xb)
{
  __shared__ float a[512];
  const int ch = blockIdx.x, b = blockIdx.y, tid = threadIdx.x;
  a[tid]     = attn[b*Ss + tid];
  a[tid+256] = attn[b*Ss + tid + 256];
  __syncthreads();
  const float* e0 = enc + (size_t)b*Ss*TWOH + ch*256 + tid;
  float s0=0.f, s1=0.f, s2=0.f, s3=0.f;
  for (int s=0; s<512; s+=4){
    s0 += a[s]   * e0[(size_t)(s  )*TWOH];
    s1 += a[s+1] * e0[(size_t)(s+1)*TWOH];
    s2 += a[s+2] * e0[(size_t)(s+2)*TWOH];
    s3 += a[s+3] * e0[(size_t)(s+3)*TWOH];
  }
  xb[b*2560 + 512 + ch*256 + tid] = f2bf(s0+s1+s2+s3);
}

// ---------------- GRU gates + h_new ----------------
__global__ void k_gates(const float* __restrict__ gx, const float* __restrict__ gh,
                        const float* __restrict__ b_ih, const float* __restrict__ b_hh,
                        const float* __restrict__ h, float* __restrict__ hnew_out,
                        short* __restrict__ hnewb)
{
  const int gid = blockIdx.x*256 + threadIdx.x;
  const int b = gid >> 10, j = gid & 1023;
  float xr = gx[b*3072 + j]        + b_ih[j];
  float xz = gx[b*3072 + 1024 + j] + b_ih[1024+j];
  float xn = gx[b*3072 + 2048 + j] + b_ih[2048+j];
  float hr = gh[b*3072 + j]        + b_hh[j];
  float hz = gh[b*3072 + 1024 + j] + b_hh[1024+j];
  float hn = gh[b*3072 + 2048 + j] + b_hh[2048+j];
  float r = 1.f/(1.f + __expf(-(xr+hr)));
  float z = 1.f/(1.f + __expf(-(xz+hz)));
  float n = tanhf(xn + r*hn);
  float hv = (1.f - z)*n + z*h[b*Hh + j];
  hnew_out[gid] = hv;
  hnewb[gid] = f2bf(hv);
}

extern "C" void kernel_launch(void* const* d_in, const int* in_sizes, int n_in,
                              void* d_out, int out_size, void* d_ws, size_t ws_size,
                              hipStream_t stream)
{
  const int*   dec   = (const int*)  d_in[0];
  const float* h     = (const float*)d_in[1];
  const float* enc   = (const float*)d_in[2];
  const float* emb   = (const float*)d_in[3];
  const float* W_ah  = (const float*)d_in[4];
  const float* b_ah  = (const float*)d_in[5];
  const float* W_ae  = (const float*)d_in[6];
  const float* b_ae  = (const float*)d_in[7];
  const float* wsc   = (const float*)d_in[8];
  const float* W_ih  = (const float*)d_in[9];
  const float* W_hh  = (const float*)d_in[10];
  const float* b_ih  = (const float*)d_in[11];
  const float* b_hh  = (const float*)d_in[12];
  const float* W_out = (const float*)d_in[13];
  const float* b_out = (const float*)d_in[14];
  float* out = (float*)d_out;
  float* hnew_out = out + (size_t)Bb*Vv;

  char* w = (char*)d_ws;
  float* scores = (float*)w;  w += (size_t)65536*4;    // zeroed (atomic target)
  float* ahb    = (float*)w;  w += (size_t)131072*4;   // zeroed
  float* ghb    = (float*)w;  w += (size_t)393216*4;   // zeroed
  float* gxb    = (float*)w;  w += (size_t)393216*4;   // zeroed
  size_t zero_bytes = (size_t)(w - (char*)d_ws);
  float* attn   = (float*)w;  w += (size_t)65536*4;
  short* waeb   = (short*)w;  w += (size_t)2097152*2;
  short* xb     = (short*)w;  w += (size_t)128*2560*2;
  short* hb     = (short*)w;  w += (size_t)131072*2;
  short* hnb    = (short*)w;  w += (size_t)131072*2;
  float* ctxp   = (float*)w;  w += (size_t)4*Bb*TWOH*4;
  short* encb   = (short*)w;  w += (size_t)65536*2048*2;
  const bool big = ((size_t)(w - (char*)d_ws) <= ws_size);

  hipMemsetAsync(d_ws, 0, zero_bytes, stream);
  k_prep<<<4096, 256, 0, stream>>>(W_ae, waeb, h, hb, dec, emb, xb);
  k_gemm128<0><<<dim3(32,2), 256, 0, stream>>>(hb, 1024, W_ah, W_hh, ahb, ghb, nullptr, 8);
  k_scores_fuse<<<1024, 512, 0, stream>>>(enc, big ? encb : nullptr, waeb,
                                          ahb, b_ah, b_ae, wsc, scores);
  k_softmax<<<128, 512, 0, stream>>>(scores, attn);
  if (big){
    k_ctx_bf16<<<512, 256, 0, stream>>>(encb, attn, ctxp);
    k_ctxfin<<<1024, 256, 0, stream>>>(ctxp, xb);
  } else {
    k_ctx_f32<<<dim3(8,128), 256, 0, stream>>>(enc, attn, xb);
  }
  k_gemm128<1><<<dim3(24,4), 256, 0, stream>>>(xb, 2560, W_ih, nullptr, gxb, nullptr, nullptr, 10);
  k_gates<<<512, 256, 0, stream>>>(gxb, ghb, b_ih, b_hh, h, hnew_out, hnb);
  k_gemm128<2><<<dim3(393,1), 256, 0, stream>>>(hnb, 1024, W_out, nullptr, out, nullptr, b_out, 16);
}

// Round 12
// 668.322 us; speedup vs baseline: 1.4501x; 1.4501x over previous
//
#include <hip/hip_runtime.h>
#include <hip/hip_bf16.h>

#define DEVI __device__ __forceinline__

typedef short bf16x8 __attribute__((ext_vector_type(8)));
typedef float f32x4  __attribute__((ext_vector_type(4)));

static constexpr int Bb   = 128;
static constexpr int Ss   = 512;
static constexpr int Hh   = 1024;
static constexpr int Ee   = 512;
static constexpr int Vv   = 50257;
static constexpr int TWOH = 2048;

DEVI short f2bf(float f){ __hip_bfloat16 h = __float2bfloat16(f); return *reinterpret_cast<short*>(&h); }
DEVI float bf2f(short s){ __hip_bfloat16 h = *reinterpret_cast<__hip_bfloat16*>(&s); return __bfloat162float(h); }

DEVI float tanh_fast(float x){            // 1 - 2/(e^2x + 1): ±inf-safe, ~1e-7 rel err
  float e = __expf(2.0f*x);
  return 1.0f - 2.0f/(e + 1.0f);
}

DEVI bf16x8 pack8(f32x4 a, f32x4 b){
  bf16x8 v;
  v[0]=f2bf(a[0]); v[1]=f2bf(a[1]); v[2]=f2bf(a[2]); v[3]=f2bf(a[3]);
  v[4]=f2bf(b[0]); v[5]=f2bf(b[1]); v[6]=f2bf(b[2]); v[7]=f2bf(b[3]);
  return v;
}

DEVI void gld_lds16(const void* g, void* l){
  __builtin_amdgcn_global_load_lds((const __attribute__((address_space(1))) void*)g,
                                   (__attribute__((address_space(3))) void*)l, 16, 0, 0);
}

DEVI f32x4 mfma16(bf16x8 a, bf16x8 b, f32x4 c){
  return __builtin_amdgcn_mfma_f32_16x16x32_bf16(a, b, c, 0, 0, 0);
}

// ---------------- enc fp32 -> bf16, fully vectorized streaming pass ----------------
// B*S*2H = 134,217,728 elems; 65536 blocks x 256 thr x 8 elems covers it exactly.
__global__ void k_enc2bf(const float* __restrict__ enc, short* __restrict__ encb)
{
  const size_t i = ((size_t)blockIdx.x*256 + threadIdx.x) * 8;
  f32x4 f0 = *(const f32x4*)(enc + i);
  f32x4 f1 = *(const f32x4*)(enc + i + 4);
  *(bf16x8*)(encb + i) = pack8(f0, f1);
}

// ---------------- prep: convert W_ae->bf16, h->bf16, gather emb into x_bf16 ----------------
__global__ void k_prep(const float* __restrict__ wae, short* __restrict__ waeb,
                       const float* __restrict__ h, short* __restrict__ hb,
                       const int* __restrict__ dec_in, const float* __restrict__ emb,
                       short* __restrict__ xb)
{
  const int total_wae = Hh*TWOH;
  const int total_h   = Bb*Hh;
  const int total_emb = Bb*Ee;
  const int total = total_wae + total_h + total_emb;
  for (int i = blockIdx.x*blockDim.x + threadIdx.x; i < total; i += gridDim.x*blockDim.x){
    if (i < total_wae) waeb[i] = f2bf(wae[i]);
    else if (i < total_wae + total_h){ int j = i - total_wae; hb[j] = f2bf(h[j]); }
    else {
      int j = i - total_wae - total_h;
      int b = j >> 9, e = j & 511;
      xb[b*2560 + e] = f2bf(emb[(size_t)dec_in[b]*Ee + e]);
    }
  }
}

// ---------------- scores GEMM: 256x256, A tri-ring LDS + B DIRECT-FROM-GLOBAL ------
// 8 waves (2M x 4N), per-wave 128x64, BK=64. B fragments are plain 16B global
// reads (swizzle-identity verified: bq[j] = waeb[n*2H + kt*64 + kk*32 + hi4*8],
// n = nb*256 + wc*64 + j*16 + lo) hitting the L2-resident 1MB panel -> B never
// touches LDS; LDS-pipe load halves (128 af reads/tile/block vs 192) and the
// mid-barrier disappears. A: bf16 encb via gld_lds tri-ring (3x32KB), distance
// 2, staged LAST in each tile so STA(t+2) is the YOUNGEST in-flight vmem op --
// vmcnt(4) at the boundary retires STA(t+1)+all bq (older, in-order count) and
// keeps exactly STA(t+2) in flight. ONE barrier per K-tile.
// XCD grouping (r8-measured FETCH 541MB): 4 same-rt blocks per XCD share the
// A panel in L2; all 4 B panels (4MB) stay L2/L3-hot.
__launch_bounds__(512)
__global__ void k_scores8(const short* __restrict__ encbf, const short* __restrict__ waeb,
                          const float* __restrict__ ahb, const float* __restrict__ b_ah,
                          const float* __restrict__ b_ae, const float* __restrict__ wsc,
                          float* __restrict__ scores)
{
  __shared__ __align__(16) char LDSB[98304];    // A tri-ring 3x32KB
  const int q  = blockIdx.x;
  const int xcd = q & 7, sl = q >> 3;
  const int rt = xcd*32 + (sl>>2), nb = sl & 3; // rt 0..255, nb 0..3 (bijective)
  const int tid = threadIdx.x, wid = tid>>6, lane = tid&63;
  const int wr = wid>>2, wc = wid&3;            // 2M x 4N waves
  const int srow = lane>>3, l7 = lane&7;
  const int lo = lane&15, hi4 = lane>>4;
  const int swk = (l7 ^ srow)*8;                // pre-swizzled source k-chunk (elems)

  const short* Ag  = encbf + (size_t)rt*256*TWOH + (size_t)(wid*8+srow)*TWOH + swk;
  const short* Bgr = waeb  + (size_t)nb*256*TWOH + (size_t)(wc*64+lo)*TWOH + hi4*8;
  char* AW = LDSB + wid*1024;                   // + buf*32768 + rnd*8192 (lane scatter implicit)
  const char* AR = LDSB + (wr*128 + lo)*128;    // + buf*32768 + i*2048 + sw
  const int sw0 = (hi4*16) ^ (l7<<4);           // kk=0 swizzled byte offset
  const int sw1 = (64 + hi4*16) ^ (l7<<4);      // kk=1

  f32x4 acc[8][4] = {};

  auto STA = [&](int buf, int kt){
    #pragma unroll
    for (int rnd=0; rnd<4; ++rnd)
      gld_lds16(Ag + (size_t)rnd*64*TWOH + kt*64, AW + buf*32768 + rnd*8192);
  };

  // prologue: stage A(0), A(1); vmcnt(4) retires A(0), keeps A(1) in flight
  STA(0,0); STA(1,1);
  asm volatile("s_waitcnt vmcnt(4)" ::: "memory");
  __builtin_amdgcn_s_barrier();
  __builtin_amdgcn_sched_barrier(0);

  int ab = 0;                                   // A ring buffer index = t%3
  for (int t = 0; t < 32; ++t){
    int ab2 = ab+2; if (ab2>=3) ab2-=3;         // (t+2)%3
    const int aO = ab*32768;
    const short* Bk = Bgr + t*64;               // this tile's B k-base
    bf16x8 af[4], bq[4];

    // ---- kk0: B from global (L2), A from LDS; 32 MFMA ----
    #pragma unroll
    for (int j=0;j<4;++j) bq[j] = *(const bf16x8*)(Bk + (size_t)j*16*TWOH);
    #pragma unroll
    for (int i=0;i<4;++i) af[i] = *(const bf16x8*)(AR + aO + i*2048 + sw0);
    __builtin_amdgcn_s_setprio(1);
    #pragma unroll
    for (int i=0;i<4;++i)
      #pragma unroll
      for (int j=0;j<4;++j)
        acc[i][j] = mfma16(af[i], bq[j], acc[i][j]);
    __builtin_amdgcn_s_setprio(0);
    #pragma unroll
    for (int i=0;i<4;++i) af[i] = *(const bf16x8*)(AR + aO + (4+i)*2048 + sw0);
    __builtin_amdgcn_s_setprio(1);
    #pragma unroll
    for (int i=0;i<4;++i)
      #pragma unroll
      for (int j=0;j<4;++j)
        acc[4+i][j] = mfma16(af[i], bq[j], acc[4+i][j]);
    __builtin_amdgcn_s_setprio(0);

    // ---- kk1 ----
    #pragma unroll
    for (int j=0;j<4;++j) bq[j] = *(const bf16x8*)(Bk + (size_t)j*16*TWOH + 32);
    #pragma unroll
    for (int i=0;i<4;++i) af[i] = *(const bf16x8*)(AR + aO + i*2048 + sw1);
    __builtin_amdgcn_s_setprio(1);
    #pragma unroll
    for (int i=0;i<4;++i)
      #pragma unroll
      for (int j=0;j<4;++j)
        acc[i][j] = mfma16(af[i], bq[j], acc[i][j]);
    __builtin_amdgcn_s_setprio(0);
    #pragma unroll
    for (int i=0;i<4;++i) af[i] = *(const bf16x8*)(AR + aO + (4+i)*2048 + sw1);
    __builtin_amdgcn_s_setprio(1);
    #pragma unroll
    for (int i=0;i<4;++i)
      #pragma unroll
      for (int j=0;j<4;++j)
        acc[4+i][j] = mfma16(af[i], bq[j], acc[4+i][j]);
    __builtin_amdgcn_s_setprio(0);

    // ---- stage A(t+2) LAST (youngest in flight), counted wait, ONE barrier ----
    if (t<30) STA(ab2, t+2);
    if (t<30)       asm volatile("s_waitcnt vmcnt(4)" ::: "memory");
    else if (t==30) asm volatile("s_waitcnt vmcnt(0)" ::: "memory");
    __builtin_amdgcn_s_barrier();
    __builtin_amdgcn_sched_barrier(0);

    ab = (ab==2) ? 0 : ab+1;
  }
  // epilogue: scores[m] += sum_n tanh(ah[b,n]+b_ah+b_ae+ae)*w_score[n]
  const int b = rt >> 1;                        // 256-row tile = half a batch row
  float w4[4], t4[4];
  #pragma unroll
  for (int j=0;j<4;++j){
    int n = nb*256 + wc*64 + j*16 + lo;
    w4[j] = wsc[n];
    t4[j] = ahb[b*Hh + n] + b_ah[n] + b_ae[n];
  }
  #pragma unroll
  for (int i=0;i<8;++i){
    #pragma unroll
    for (int q2=0;q2<4;++q2){
      int m = rt*256 + wr*128 + i*16 + hi4*4 + q2;
      float s = 0.f;
      #pragma unroll
      for (int j=0;j<4;++j) s += tanh_fast(t4[j] + acc[i][j][q2]) * w4[j];
      s += __shfl_xor(s,1); s += __shfl_xor(s,2); s += __shfl_xor(s,4); s += __shfl_xor(s,8);
      if (lo == 0) atomicAdd(&scores[m], s);
    }
  }
}

// ---------------- fallback scores (fp32 enc, 2-phase dbuf) — small-ws path only ----
__launch_bounds__(512)
__global__ void k_scores_f32(const float* __restrict__ enc, const short* __restrict__ waeb,
                             const float* __restrict__ ahb, const float* __restrict__ b_ah,
                             const float* __restrict__ b_ae, const float* __restrict__ wsc,
                             float* __restrict__ scores)
{
  __shared__ __align__(16) short As[2][128*64];
  __shared__ __align__(16) short Bs[2][256*64];
  const int p  = blockIdx.x;
  const int rt = p >> 2, nb = p & 3;
  const int tid = threadIdx.x, wid = tid>>6, lane = tid&63;
  const int wr = wid>>2, wc = wid&3;
  const int srow = lane>>3, l7 = lane&7;
  const int swk = (l7 ^ srow) * 8;
  f32x4 acc[4][4] = {};
  const float* Af  = enc  + (size_t)rt*128*TWOH;
  const short* Bbp = waeb + (size_t)nb*256*TWOH;
  f32x4 pa0[2], pa1[2];

  auto stageB = [&](int s, int kt){
    #pragma unroll
    for (int i=0;i<4;++i){
      int c = wid*4+i, row = c*8+srow;
      gld_lds16(Bbp + (size_t)row*TWOH + kt*64 + swk, (char*)Bs[s] + c*1024);
    }
  };
  auto prefA = [&](int kt){
    #pragma unroll
    for (int i=0;i<2;++i){
      int row = (wid*2+i)*8+srow;
      const float* bp = Af + (size_t)row*TWOH + kt*64 + l7*8;
      pa0[i] = *(const f32x4*)bp; pa1[i] = *(const f32x4*)(bp+4);
    }
  };
  auto commitA = [&](int s){
    #pragma unroll
    for (int i=0;i<2;++i){
      int row = (wid*2+i)*8+srow;
      *(bf16x8*)((char*)As[s] + row*128 + ((l7^srow)<<4)) = pack8(pa0[i], pa1[i]);
    }
  };

  prefA(0); commitA(0); stageB(0,0);
  __syncthreads();
  int cur = 0;
  for (int kt=0; kt<32; ++kt){
    if (kt<31){ prefA(kt+1); stageB(cur^1, kt+1); }
    #pragma unroll
    for (int kk=0;kk<2;++kk){
      bf16x8 af[4], bq[4];
      const int sw = (kk*64 + (lane>>4)*16) ^ (l7<<4);
      #pragma unroll
      for (int i=0;i<4;++i) af[i] = *(const bf16x8*)((const char*)As[cur] + (wr*64+i*16+(lane&15))*128 + sw);
      #pragma unroll
      for (int j=0;j<4;++j) bq[j] = *(const bf16x8*)((const char*)Bs[cur] + (wc*64+j*16+(lane&15))*128 + sw);
      #pragma unroll
      for (int i=0;i<4;++i)
        #pragma unroll
        for (int j=0;j<4;++j)
          acc[i][j] = mfma16(af[i], bq[j], acc[i][j]);
    }
    if (kt<31) commitA(cur^1);
    __syncthreads();
    cur ^= 1;
  }
  const int lo = lane&15, hi = lane>>4;
  const int b = rt>>2;
  float w4[4], t4[4];
  #pragma unroll
  for (int j=0;j<4;++j){
    int n = nb*256 + wc*64 + j*16 + lo;
    w4[j] = wsc[n];
    t4[j] = ahb[b*Hh + n] + b_ah[n] + b_ae[n];
  }
  #pragma unroll
  for (int i=0;i<4;++i){
    #pragma unroll
    for (int q2=0;q2<4;++q2){
      int m = rt*128 + wr*64 + i*16 + hi*4 + q2;
      float s = 0.f;
      #pragma unroll
      for (int j=0;j<4;++j) s += tanhf(t4[j] + acc[i][j][q2]) * w4[j];
      s += __shfl_xor(s,1); s += __shfl_xor(s,2); s += __shfl_xor(s,4); s += __shfl_xor(s,8);
      if (lo == 0) atomicAdd(&scores[m], s);
    }
  }
}

// ---------------- generic 128-row GEMM: A[128,K] bf16 ws, B[N,K] fp32 global --------------
template<int MODE>
__launch_bounds__(256)
__global__ void k_gemm128(const short* __restrict__ A, int lda,
                          const float* __restrict__ B0, const float* __restrict__ B1,
                          float* __restrict__ O0, float* __restrict__ O1,
                          const float* __restrict__ bias, int kiters)
{
  __shared__ __align__(16) short As[2][128*64];
  __shared__ __align__(16) short Bs[2][128*64];
  const int nb = blockIdx.x;
  const int tid = threadIdx.x, wid = tid>>6, lane = tid&63;
  const int wr = wid>>1, wc = wid&1;
  const int srow = lane>>3, l7 = lane&7;
  const int swk = (l7 ^ srow) * 8;

  const float* Bt; int noff; float* Ot; int ostride;
  if constexpr (MODE==0){
    if (nb < 8){ Bt = B0; noff = 0;    Ot = O0; ostride = Hh;   }
    else       { Bt = B1; noff = 1024; Ot = O1; ostride = 3*Hh; }
  } else if constexpr (MODE==1){ Bt = B0; noff = 0; Ot = O0; ostride = 3*Hh; }
  else { Bt = B0; noff = 0; Ot = O0; ostride = Vv; }

  f32x4 acc[4][4] = {};
  f32x4 pb0[4], pb1[4];

  auto stageA = [&](int s, int kt){
    #pragma unroll
    for (int i=0;i<4;++i){
      int c = wid*4+i, row = c*8+srow;
      gld_lds16(A + (size_t)row*lda + kt*64 + swk, (char*)As[s] + c*1024);
    }
  };
  auto prefB = [&](int kt){
    #pragma unroll
    for (int i=0;i<4;++i){
      int row = (wid*4+i)*8+srow;
      int n = nb*128 + row - noff;
      if constexpr (MODE==2) n = (n > Vv-1) ? (Vv-1) : n;
      const float* bp = Bt + (size_t)n*lda + kt*64 + l7*8;
      pb0[i] = *(const f32x4*)bp; pb1[i] = *(const f32x4*)(bp+4);
    }
  };
  auto commitB = [&](int s){
    #pragma unroll
    for (int i=0;i<4;++i){
      int row = (wid*4+i)*8+srow;
      *(bf16x8*)((char*)Bs[s] + row*128 + ((l7^srow)<<4)) = pack8(pb0[i], pb1[i]);
    }
  };

  const int kt0 = blockIdx.y * kiters, kend = kt0 + kiters;
  stageA(0, kt0); prefB(kt0); commitB(0);
  __syncthreads();

  int cur = 0;
  for (int kt = kt0; kt < kend; ++kt){
    if (kt+1 < kend){ stageA(cur^1, kt+1); prefB(kt+1); }
    #pragma unroll
    for (int kk=0;kk<2;++kk){
      bf16x8 af[4], bq[4];
      const int sw = (kk*64 + (lane>>4)*16) ^ (l7<<4);
      #pragma unroll
      for (int i=0;i<4;++i) af[i] = *(const bf16x8*)((const char*)As[cur] + (wr*64+i*16+(lane&15))*128 + sw);
      #pragma unroll
      for (int j=0;j<4;++j) bq[j] = *(const bf16x8*)((const char*)Bs[cur] + (wc*64+j*16+(lane&15))*128 + sw);
      #pragma unroll
      for (int i=0;i<4;++i)
        #pragma unroll
        for (int j=0;j<4;++j)
          acc[i][j] = mfma16(af[i], bq[j], acc[i][j]);
    }
    if (kt+1 < kend) commitB(cur^1);
    __syncthreads();
    cur ^= 1;
  }
  const int lo = lane&15, hi = lane>>4;
  #pragma unroll
  for (int i=0;i<4;++i){
    #pragma unroll
    for (int j=0;j<4;++j){
      int n = nb*128 + wc*64 + j*16 + lo - noff;
      #pragma unroll
      for (int q=0;q<4;++q){
        int m = wr*64 + i*16 + hi*4 + q;
        float v = acc[i][j][q];
        if constexpr (MODE==2){
          if (n < Vv) O0[(size_t)m*Vv + n] = v + bias[n];
        } else {
          atomicAdd(&Ot[(size_t)m*ostride + n], v);
        }
      }
    }
  }
}

// ---------------- softmax over S=512 per batch row ----------------
__global__ void k_softmax(const float* __restrict__ scores, float* __restrict__ attn)
{
  __shared__ float red[512];
  const int b = blockIdx.x, tid = threadIdx.x;
  float v = scores[b*Ss + tid];
  red[tid] = v; __syncthreads();
  for (int off=256; off>0; off>>=1){ if (tid<off) red[tid] = fmaxf(red[tid], red[tid+off]); __syncthreads(); }
  float mx = red[0]; __syncthreads();
  float e = __expf(v - mx);
  red[tid] = e; __syncthreads();
  for (int off=256; off>0; off>>=1){ if (tid<off) red[tid] += red[tid+off]; __syncthreads(); }
  attn[b*Ss + tid] = e / red[0];
}

// ---------------- ctx partial: bf16 enc, 4 row-chunks of 128, vectorized ----------------
__global__ void k_ctx_bf16(const short* __restrict__ encb, const float* __restrict__ attn,
                           float* __restrict__ ctxp)
{
  __shared__ float a[128];
  const int bid = blockIdx.x, b = bid>>2, ch = bid&3, tid = threadIdx.x;
  if (tid < 128) a[tid] = attn[b*Ss + ch*128 + tid];
  __syncthreads();
  const short* e0 = encb + (size_t)(b*Ss + ch*128)*TWOH + tid*8;
  float s[8] = {};
  for (int r=0; r<128; ++r){
    bf16x8 v = *(const bf16x8*)(e0 + (size_t)r*TWOH);
    float w = a[r];
    #pragma unroll
    for (int j=0;j<8;++j) s[j] += w * bf2f(v[j]);
  }
  float* o = ctxp + (size_t)ch*Bb*TWOH + (size_t)b*TWOH + tid*8;
  #pragma unroll
  for (int j=0;j<8;++j) o[j] = s[j];
}

__global__ void k_ctxfin(const float* __restrict__ ctxp, short* __restrict__ xb)
{
  const int g = blockIdx.x*256 + threadIdx.x;
  const int b = g >> 11, col = g & 2047;
  const int N = Bb*TWOH;
  float v = ctxp[g] + ctxp[N+g] + ctxp[2*N+g] + ctxp[3*N+g];
  xb[b*2560 + 512 + col] = f2bf(v);
}

// fallback (small ws): fp32 enc, writes xb directly
__global__ void k_ctx_f32(const float* __restrict__ enc, const float* __restrict__ attn,
                          short* __restrict__ xb)
{
  __shared__ float a[512];
  const int ch = blockIdx.x, b = blockIdx.y, tid = threadIdx.x;
  a[tid]     = attn[b*Ss + tid];
  a[tid+256] = attn[b*Ss + tid + 256];
  __syncthreads();
  const float* e0 = enc + (size_t)b*Ss*TWOH + ch*256 + tid;
  float s0=0.f, s1=0.f, s2=0.f, s3=0.f;
  for (int s=0; s<512; s+=4){
    s0 += a[s]   * e0[(size_t)(s  )*TWOH];
    s1 += a[s+1] * e0[(size_t)(s+1)*TWOH];
    s2 += a[s+2] * e0[(size_t)(s+2)*TWOH];
    s3 += a[s+3] * e0[(size_t)(s+3)*TWOH];
  }
  xb[b*2560 + 512 + ch*256 + tid] = f2bf(s0+s1+s2+s3);
}

// ---------------- GRU gates + h_new ----------------
__global__ void k_gates(const float* __restrict__ gx, const float* __restrict__ gh,
                        const float* __restrict__ b_ih, const float* __restrict__ b_hh,
                        const float* __restrict__ h, float* __restrict__ hnew_out,
                        short* __restrict__ hnewb)
{
  const int gid = blockIdx.x*256 + threadIdx.x;
  const int b = gid >> 10, j = gid & 1023;
  float xr = gx[b*3072 + j]        + b_ih[j];
  float xz = gx[b*3072 + 1024 + j] + b_ih[1024+j];
  float xn = gx[b*3072 + 2048 + j] + b_ih[2048+j];
  float hr = gh[b*3072 + j]        + b_hh[j];
  float hz = gh[b*3072 + 1024 + j] + b_hh[1024+j];
  float hn = gh[b*3072 + 2048 + j] + b_hh[2048+j];
  float r = 1.f/(1.f + __expf(-(xr+hr)));
  float z = 1.f/(1.f + __expf(-(xz+hz)));
  float n = tanhf(xn + r*hn);
  float hv = (1.f - z)*n + z*h[b*Hh + j];
  hnew_out[gid] = hv;
  hnewb[gid] = f2bf(hv);
}

extern "C" void kernel_launch(void* const* d_in, const int* in_sizes, int n_in,
                              void* d_out, int out_size, void* d_ws, size_t ws_size,
                              hipStream_t stream)
{
  const int*   dec   = (const int*)  d_in[0];
  const float* h     = (const float*)d_in[1];
  const float* enc   = (const float*)d_in[2];
  const float* emb   = (const float*)d_in[3];
  const float* W_ah  = (const float*)d_in[4];
  const float* b_ah  = (const float*)d_in[5];
  const float* W_ae  = (const float*)d_in[6];
  const float* b_ae  = (const float*)d_in[7];
  const float* wsc   = (const float*)d_in[8];
  const float* W_ih  = (const float*)d_in[9];
  const float* W_hh  = (const float*)d_in[10];
  const float* b_ih  = (const float*)d_in[11];
  const float* b_hh  = (const float*)d_in[12];
  const float* W_out = (const float*)d_in[13];
  const float* b_out = (const float*)d_in[14];
  float* out = (float*)d_out;
  float* hnew_out = out + (size_t)Bb*Vv;

  char* w = (char*)d_ws;
  float* scores = (float*)w;  w += (size_t)65536*4;    // zeroed (atomic target)
  float* ahb    = (float*)w;  w += (size_t)131072*4;   // zeroed
  float* ghb    = (float*)w;  w += (size_t)393216*4;   // zeroed
  float* gxb    = (float*)w;  w += (size_t)393216*4;   // zeroed
  size_t zero_bytes = (size_t)(w - (char*)d_ws);
  float* attn   = (float*)w;  w += (size_t)65536*4;
  short* waeb   = (short*)w;  w += (size_t)2097152*2;
  short* xb     = (short*)w;  w += (size_t)128*2560*2;
  short* hb     = (short*)w;  w += (size_t)131072*2;
  short* hnb    = (short*)w;  w += (size_t)131072*2;
  float* ctxp   = (float*)w;  w += (size_t)4*Bb*TWOH*4;
  short* encb   = (short*)w;  w += (size_t)65536*2048*2;
  const bool big = ((size_t)(w - (char*)d_ws) <= ws_size);

  hipMemsetAsync(d_ws, 0, zero_bytes, stream);
  if (big) k_enc2bf<<<65536, 256, 0, stream>>>(enc, encb);
  k_prep<<<4096, 256, 0, stream>>>(W_ae, waeb, h, hb, dec, emb, xb);
  k_gemm128<0><<<dim3(32,2), 256, 0, stream>>>(hb, 1024, W_ah, W_hh, ahb, ghb, nullptr, 8);
  if (big)
    k_scores8<<<1024, 512, 0, stream>>>(encb, waeb, ahb, b_ah, b_ae, wsc, scores);
  else
    k_scores_f32<<<2048, 512, 0, stream>>>(enc, waeb, ahb, b_ah, b_ae, wsc, scores);
  k_softmax<<<128, 512, 0, stream>>>(scores, attn);
  if (big){
    k_ctx_bf16<<<512, 256, 0, stream>>>(encb, attn, ctxp);
    k_ctxfin<<<1024, 256, 0, stream>>>(ctxp, xb);
  } else {
    k_ctx_f32<<<dim3(8,128), 256, 0, stream>>>(enc, attn, xb);
  }
  k_gemm128<1><<<dim3(24,4), 256, 0, stream>>>(xb, 2560, W_ih, nullptr, gxb, nullptr, nullptr, 10);
  k_gates<<<512, 256, 0, stream>>>(gxb, ghb, b_ih, b_hh, h, hnew_out, hnb);
  k_gemm128<2><<<dim3(393,1), 256, 0, stream>>>(hnb, 1024, W_out, nullptr, out, nullptr, b_out, 16);
}

// Round 13
// 595.552 us; speedup vs baseline: 1.6273x; 1.1222x over previous
//
#include <hip/hip_runtime.h>
#include <hip/hip_bf16.h>

#define DEVI __device__ __forceinline__

typedef short bf16x8 __attribute__((ext_vector_type(8)));
typedef float f32x4  __attribute__((ext_vector_type(4)));

static constexpr int Bb   = 128;
static constexpr int Ss   = 512;
static constexpr int Hh   = 1024;
static constexpr int Ee   = 512;
static constexpr int Vv   = 50257;
static constexpr int TWOH = 2048;

DEVI short f2bf(float f){ __hip_bfloat16 h = __float2bfloat16(f); return *reinterpret_cast<short*>(&h); }
DEVI float bf2f(short s){ __hip_bfloat16 h = *reinterpret_cast<__hip_bfloat16*>(&s); return __bfloat162float(h); }

DEVI float tanh_fast(float x){            // 1 - 2/(e^2x + 1): ±inf-safe, ~1e-7 rel err
  float e = __expf(2.0f*x);
  return 1.0f - 2.0f/(e + 1.0f);
}

DEVI bf16x8 pack8(f32x4 a, f32x4 b){
  bf16x8 v;
  v[0]=f2bf(a[0]); v[1]=f2bf(a[1]); v[2]=f2bf(a[2]); v[3]=f2bf(a[3]);
  v[4]=f2bf(b[0]); v[5]=f2bf(b[1]); v[6]=f2bf(b[2]); v[7]=f2bf(b[3]);
  return v;
}

DEVI void gld_lds16(const void* g, void* l){
  __builtin_amdgcn_global_load_lds((const __attribute__((address_space(1))) void*)g,
                                   (__attribute__((address_space(3))) void*)l, 16, 0, 0);
}

DEVI f32x4 mfma16(bf16x8 a, bf16x8 b, f32x4 c){
  return __builtin_amdgcn_mfma_f32_16x16x32_bf16(a, b, c, 0, 0, 0);
}

// ---------------- prep: convert W_ae->bf16, h->bf16, gather emb into x_bf16 ----------------
__global__ void k_prep(const float* __restrict__ wae, short* __restrict__ waeb,
                       const float* __restrict__ h, short* __restrict__ hb,
                       const int* __restrict__ dec_in, const float* __restrict__ emb,
                       short* __restrict__ xb)
{
  const int total_wae = Hh*TWOH;
  const int total_h   = Bb*Hh;
  const int total_emb = Bb*Ee;
  const int total = total_wae + total_h + total_emb;
  for (int i = blockIdx.x*blockDim.x + threadIdx.x; i < total; i += gridDim.x*blockDim.x){
    if (i < total_wae) waeb[i] = f2bf(wae[i]);
    else if (i < total_wae + total_h){ int j = i - total_wae; hb[j] = f2bf(h[j]); }
    else {
      int j = i - total_wae - total_h;
      int b = j >> 9, e = j & 511;
      xb[b*2560 + e] = f2bf(emb[(size_t)dec_in[b]*Ee + e]);
    }
  }
}

// ---------------- scores GEMM: PERSISTENT-rt MULTI-PASS (replaces enc2bf + k_scores8) ------
// Grid 256 (1 block/CU). Block rt owns A rows [rt*256, rt*256+256) EXCLUSIVELY and
// loops nb=0..3 over the 1024 output columns.
//   Pass 0 (r10's proven structure): A reg-staged fp32->bf16 (PREFA/COMMITA), GEMM
//     vs B panel 0, AND writes the converted panel to encb (conversion rides the
//     MFMA slack). Correctness by in-order vmem retirement: COMMITA's register-dep
//     wait on PREFA(t+1) retires the older STB(t+1) before the tile barrier.
//   Passes 1-3 (r9's proven structure): A re-read from encb via gld_lds tri-ring
//     (3x32KB, distance-2), B dbuf (2x32KB), counted vmcnt(4), 2 barriers/tile.
//     encb is L2-HOT (this block wrote it moments ago, same XCD).
// Pass-0 boundary: vmcnt(0)+barrier so encb stores are ack'd before re-read.
// LDS 160KB total. B panels (4MB bf16) are L2/L3-resident everywhere.
__launch_bounds__(512)
__global__ void k_scores_mp(const float* __restrict__ enc, short* __restrict__ encb,
                            const short* __restrict__ waeb,
                            const float* __restrict__ ahb, const float* __restrict__ b_ah,
                            const float* __restrict__ b_ae, const float* __restrict__ wsc,
                            float* __restrict__ scores)
{
  __shared__ __align__(16) char LDSB[163840];   // A ring 3x32KB @0; B dbuf 2x32KB @98304
  const int rt = blockIdx.x;                    // 0..255
  const int tid = threadIdx.x, wid = tid>>6, lane = tid&63;
  const int wr = wid>>2, wc = wid&3;            // 2M x 4N waves
  const int srow = lane>>3, l7 = lane&7;
  const int lo = lane&15, hi4 = lane>>4;
  const int swk = (l7 ^ srow)*8;                // pre-swizzled source k-chunk (elems)

  const float* Agf = enc  + (size_t)rt*256*TWOH + (size_t)(wid*8+srow)*TWOH + swk;
  const short* Agb = encb + (size_t)rt*256*TWOH + (size_t)(wid*8+srow)*TWOH + swk;
  short*       Eg  = encb + (size_t)rt*256*TWOH + (size_t)(wid*8+srow)*TWOH + swk;

  char* AW  = LDSB + wid*1024;                  // gld_lds dest base (lane scatter implicit)
  char* AWc = LDSB + wid*1024 + lane*16;        // ds_write dest (explicit lane)
  char* BW  = LDSB + 98304 + wid*1024;
  const char* AR = LDSB + (wr*128 + lo)*128;    // + buf*32768 + i*2048 + sw
  const char* BR = LDSB + 98304 + (wc*64 + lo)*128;
  const int sw0 = (hi4*16) ^ (l7<<4);
  const int sw1 = (64 + hi4*16) ^ (l7<<4);

  f32x4 acc[8][4];
  f32x4 pa[4][2];
  const short* Bg = waeb + (size_t)(wid*8+srow)*TWOH + swk;   // nb=0 panel

  auto ZERO = [&](){
    #pragma unroll
    for (int i=0;i<8;++i)
      #pragma unroll
      for (int j=0;j<4;++j) acc[i][j] = (f32x4){0.f,0.f,0.f,0.f};
  };
  auto STB = [&](int buf, int kt){
    #pragma unroll
    for (int rnd=0; rnd<4; ++rnd)
      gld_lds16(Bg + (size_t)rnd*64*TWOH + kt*64, BW + buf*32768 + rnd*8192);
  };
  auto STA = [&](int buf, int kt){              // bf16 A from encb (passes 1-3)
    #pragma unroll
    for (int rnd=0; rnd<4; ++rnd)
      gld_lds16(Agb + (size_t)rnd*64*TWOH + kt*64, AW + buf*32768 + rnd*8192);
  };
  auto PREFA = [&](int kt){                     // fp32 A regs (pass 0)
    #pragma unroll
    for (int rnd=0; rnd<4; ++rnd){
      const float* p = Agf + (size_t)rnd*64*TWOH + kt*64;
      pa[rnd][0] = *(const f32x4*)p; pa[rnd][1] = *(const f32x4*)(p+4);
    }
  };
  auto COMMITA = [&](int buf){
    #pragma unroll
    for (int rnd=0; rnd<4; ++rnd)
      *(bf16x8*)(AWc + buf*32768 + rnd*8192) = pack8(pa[rnd][0], pa[rnd][1]);
  };
  auto STOREE = [&](int kt){
    #pragma unroll
    for (int rnd=0; rnd<4; ++rnd)
      *(bf16x8*)(Eg + (size_t)rnd*64*TWOH + kt*64) = pack8(pa[rnd][0], pa[rnd][1]);
  };
  auto KKHALF = [&](int aO, int bO, int sw){    // 8 A-reads + 4 B-reads + 32 MFMA
    bf16x8 af[4], bq[4];
    #pragma unroll
    for (int j=0;j<4;++j) bq[j] = *(const bf16x8*)(BR + bO + j*2048 + sw);
    #pragma unroll
    for (int i=0;i<4;++i) af[i] = *(const bf16x8*)(AR + aO + i*2048 + sw);
    __builtin_amdgcn_s_setprio(1);
    #pragma unroll
    for (int i=0;i<4;++i)
      #pragma unroll
      for (int j=0;j<4;++j)
        acc[i][j] = mfma16(af[i], bq[j], acc[i][j]);
    __builtin_amdgcn_s_setprio(0);
    #pragma unroll
    for (int i=0;i<4;++i) af[i] = *(const bf16x8*)(AR + aO + (4+i)*2048 + sw);
    __builtin_amdgcn_s_setprio(1);
    #pragma unroll
    for (int i=0;i<4;++i)
      #pragma unroll
      for (int j=0;j<4;++j)
        acc[4+i][j] = mfma16(af[i], bq[j], acc[4+i][j]);
    __builtin_amdgcn_s_setprio(0);
  };
  auto EPI = [&](int nbv){
    const int b = rt >> 1;
    float w4[4], t4[4];
    #pragma unroll
    for (int j=0;j<4;++j){
      int n = nbv*256 + wc*64 + j*16 + lo;
      w4[j] = wsc[n];
      t4[j] = ahb[b*Hh + n] + b_ah[n] + b_ae[n];
    }
    #pragma unroll
    for (int i=0;i<8;++i){
      #pragma unroll
      for (int q2=0;q2<4;++q2){
        int m = rt*256 + wr*128 + i*16 + hi4*4 + q2;
        float s = 0.f;
        #pragma unroll
        for (int j=0;j<4;++j) s += tanh_fast(t4[j] + acc[i][j][q2]) * w4[j];
        s += __shfl_xor(s,1); s += __shfl_xor(s,2); s += __shfl_xor(s,4); s += __shfl_xor(s,8);
        if (lo == 0) atomicAdd(&scores[m], s);
      }
    }
  };

  // ================= pass 0: fp32 A + convert + encb write (r10 structure) =========
  ZERO();
  STB(0,0);                 // oldest -> retired by COMMITA's PREFA register wait
  PREFA(0); COMMITA(0); STOREE(0);
  PREFA(1);
  asm volatile("s_waitcnt lgkmcnt(0)" ::: "memory");
  __builtin_amdgcn_s_barrier();
  __builtin_amdgcn_sched_barrier(0);

  for (int t = 0; t < 32; ++t){
    const int cur = t&1, nxt = cur^1;
    const int aO = cur*32768, bO = cur*32768;
    if (t<31){ STB(nxt, t+1); PREFA(t+1); }
    KKHALF(aO, bO, sw0);
    if (t<31){ COMMITA(nxt); STOREE(t+1); }     // reg wait retires STB(t+1) (older)
    KKHALF(aO, bO, sw1);
    asm volatile("s_waitcnt lgkmcnt(0)" ::: "memory");
    __builtin_amdgcn_s_barrier();
    __builtin_amdgcn_sched_barrier(0);
  }
  EPI(0);
  asm volatile("s_waitcnt vmcnt(0)" ::: "memory");   // encb stores ack'd
  __builtin_amdgcn_s_barrier();

  // ================= passes 1-3: bf16 A tri-ring from L2-hot encb (r9 structure) ===
  for (int nbv = 1; nbv < 4; ++nbv){
    Bg = waeb + (size_t)nbv*256*TWOH + (size_t)(wid*8+srow)*TWOH + swk;
    ZERO();
    STA(0,0); STB(0,0); STA(1,1);
    asm volatile("s_waitcnt vmcnt(4)" ::: "memory");  // retires STA(0)+STB(0)
    __builtin_amdgcn_s_barrier();
    __builtin_amdgcn_sched_barrier(0);

    int ab = 0;
    for (int t = 0; t < 32; ++t){
      int ab2 = ab+2; if (ab2>=3) ab2-=3;
      const int aO = ab*32768, bO = (t&1)*32768;

      if (t<31) STB((t+1)&1, t+1);
      KKHALF(aO, bO, sw0);
      __builtin_amdgcn_s_barrier();               // pins STB before STA(t+2)

      if (t<30) STA(ab2, t+2);
      KKHALF(aO, bO, sw1);
      if (t<30)       asm volatile("s_waitcnt vmcnt(4)" ::: "memory");
      else if (t==30) asm volatile("s_waitcnt vmcnt(0)" ::: "memory");
      __builtin_amdgcn_s_barrier();
      __builtin_amdgcn_sched_barrier(0);

      ab = (ab==2) ? 0 : ab+1;
    }
    EPI(nbv);
  }
}

// ---------------- fallback scores (fp32 enc, 2-phase dbuf) — small-ws path only ----
__launch_bounds__(512)
__global__ void k_scores_f32(const float* __restrict__ enc, const short* __restrict__ waeb,
                             const float* __restrict__ ahb, const float* __restrict__ b_ah,
                             const float* __restrict__ b_ae, const float* __restrict__ wsc,
                             float* __restrict__ scores)
{
  __shared__ __align__(16) short As[2][128*64];
  __shared__ __align__(16) short Bs[2][256*64];
  const int p  = blockIdx.x;
  const int rt = p >> 2, nb = p & 3;
  const int tid = threadIdx.x, wid = tid>>6, lane = tid&63;
  const int wr = wid>>2, wc = wid&3;
  const int srow = lane>>3, l7 = lane&7;
  const int swk = (l7 ^ srow) * 8;
  f32x4 acc[4][4] = {};
  const float* Af  = enc  + (size_t)rt*128*TWOH;
  const short* Bbp = waeb + (size_t)nb*256*TWOH;
  f32x4 pa0[2], pa1[2];

  auto stageB = [&](int s, int kt){
    #pragma unroll
    for (int i=0;i<4;++i){
      int c = wid*4+i, row = c*8+srow;
      gld_lds16(Bbp + (size_t)row*TWOH + kt*64 + swk, (char*)Bs[s] + c*1024);
    }
  };
  auto prefA = [&](int kt){
    #pragma unroll
    for (int i=0;i<2;++i){
      int row = (wid*2+i)*8+srow;
      const float* bp = Af + (size_t)row*TWOH + kt*64 + l7*8;
      pa0[i] = *(const f32x4*)bp; pa1[i] = *(const f32x4*)(bp+4);
    }
  };
  auto commitA = [&](int s){
    #pragma unroll
    for (int i=0;i<2;++i){
      int row = (wid*2+i)*8+srow;
      *(bf16x8*)((char*)As[s] + row*128 + ((l7^srow)<<4)) = pack8(pa0[i], pa1[i]);
    }
  };

  prefA(0); commitA(0); stageB(0,0);
  __syncthreads();
  int cur = 0;
  for (int kt=0; kt<32; ++kt){
    if (kt<31){ prefA(kt+1); stageB(cur^1, kt+1); }
    #pragma unroll
    for (int kk=0;kk<2;++kk){
      bf16x8 af[4], bq[4];
      const int sw = (kk*64 + (lane>>4)*16) ^ (l7<<4);
      #pragma unroll
      for (int i=0;i<4;++i) af[i] = *(const bf16x8*)((const char*)As[cur] + (wr*64+i*16+(lane&15))*128 + sw);
      #pragma unroll
      for (int j=0;j<4;++j) bq[j] = *(const bf16x8*)((const char*)Bs[cur] + (wc*64+j*16+(lane&15))*128 + sw);
      #pragma unroll
      for (int i=0;i<4;++i)
        #pragma unroll
        for (int j=0;j<4;++j)
          acc[i][j] = mfma16(af[i], bq[j], acc[i][j]);
    }
    if (kt<31) commitA(cur^1);
    __syncthreads();
    cur ^= 1;
  }
  const int lo = lane&15, hi = lane>>4;
  const int b = rt>>2;
  float w4[4], t4[4];
  #pragma unroll
  for (int j=0;j<4;++j){
    int n = nb*256 + wc*64 + j*16 + lo;
    w4[j] = wsc[n];
    t4[j] = ahb[b*Hh + n] + b_ah[n] + b_ae[n];
  }
  #pragma unroll
  for (int i=0;i<4;++i){
    #pragma unroll
    for (int q2=0;q2<4;++q2){
      int m = rt*128 + wr*64 + i*16 + hi*4 + q2;
      float s = 0.f;
      #pragma unroll
      for (int j=0;j<4;++j) s += tanhf(t4[j] + acc[i][j][q2]) * w4[j];
      s += __shfl_xor(s,1); s += __shfl_xor(s,2); s += __shfl_xor(s,4); s += __shfl_xor(s,8);
      if (lo == 0) atomicAdd(&scores[m], s);
    }
  }
}

// ---------------- generic 128-row GEMM: A[128,K] bf16 ws, B[N,K] fp32 global --------------
template<int MODE>
__launch_bounds__(256)
__global__ void k_gemm128(const short* __restrict__ A, int lda,
                          const float* __restrict__ B0, const float* __restrict__ B1,
                          float* __restrict__ O0, float* __restrict__ O1,
                          const float* __restrict__ bias, int kiters)
{
  __shared__ __align__(16) short As[2][128*64];
  __shared__ __align__(16) short Bs[2][128*64];
  const int nb = blockIdx.x;
  const int tid = threadIdx.x, wid = tid>>6, lane = tid&63;
  const int wr = wid>>1, wc = wid&1;
  const int srow = lane>>3, l7 = lane&7;
  const int swk = (l7 ^ srow) * 8;

  const float* Bt; int noff; float* Ot; int ostride;
  if constexpr (MODE==0){
    if (nb < 8){ Bt = B0; noff = 0;    Ot = O0; ostride = Hh;   }
    else       { Bt = B1; noff = 1024; Ot = O1; ostride = 3*Hh; }
  } else if constexpr (MODE==1){ Bt = B0; noff = 0; Ot = O0; ostride = 3*Hh; }
  else { Bt = B0; noff = 0; Ot = O0; ostride = Vv; }

  f32x4 acc[4][4] = {};
  f32x4 pb0[4], pb1[4];

  auto stageA = [&](int s, int kt){
    #pragma unroll
    for (int i=0;i<4;++i){
      int c = wid*4+i, row = c*8+srow;
      gld_lds16(A + (size_t)row*lda + kt*64 + swk, (char*)As[s] + c*1024);
    }
  };
  auto prefB = [&](int kt){
    #pragma unroll
    for (int i=0;i<4;++i){
      int row = (wid*4+i)*8+srow;
      int n = nb*128 + row - noff;
      if constexpr (MODE==2) n = (n > Vv-1) ? (Vv-1) : n;
      const float* bp = Bt + (size_t)n*lda + kt*64 + l7*8;
      pb0[i] = *(const f32x4*)bp; pb1[i] = *(const f32x4*)(bp+4);
    }
  };
  auto commitB = [&](int s){
    #pragma unroll
    for (int i=0;i<4;++i){
      int row = (wid*4+i)*8+srow;
      *(bf16x8*)((char*)Bs[s] + row*128 + ((l7^srow)<<4)) = pack8(pb0[i], pb1[i]);
    }
  };

  const int kt0 = blockIdx.y * kiters, kend = kt0 + kiters;
  stageA(0, kt0); prefB(kt0); commitB(0);
  __syncthreads();

  int cur = 0;
  for (int kt = kt0; kt < kend; ++kt){
    if (kt+1 < kend){ stageA(cur^1, kt+1); prefB(kt+1); }
    #pragma unroll
    for (int kk=0;kk<2;++kk){
      bf16x8 af[4], bq[4];
      const int sw = (kk*64 + (lane>>4)*16) ^ (l7<<4);
      #pragma unroll
      for (int i=0;i<4;++i) af[i] = *(const bf16x8*)((const char*)As[cur] + (wr*64+i*16+(lane&15))*128 + sw);
      #pragma unroll
      for (int j=0;j<4;++j) bq[j] = *(const bf16x8*)((const char*)Bs[cur] + (wc*64+j*16+(lane&15))*128 + sw);
      #pragma unroll
      for (int i=0;i<4;++i)
        #pragma unroll
        for (int j=0;j<4;++j)
          acc[i][j] = mfma16(af[i], bq[j], acc[i][j]);
    }
    if (kt+1 < kend) commitB(cur^1);
    __syncthreads();
    cur ^= 1;
  }
  const int lo = lane&15, hi = lane>>4;
  #pragma unroll
  for (int i=0;i<4;++i){
    #pragma unroll
    for (int j=0;j<4;++j){
      int n = nb*128 + wc*64 + j*16 + lo - noff;
      #pragma unroll
      for (int q=0;q<4;++q){
        int m = wr*64 + i*16 + hi*4 + q;
        float v = acc[i][j][q];
        if constexpr (MODE==2){
          if (n < Vv) O0[(size_t)m*Vv + n] = v + bias[n];
        } else {
          atomicAdd(&Ot[(size_t)m*ostride + n], v);
        }
      }
    }
  }
}

// ---------------- softmax over S=512 per batch row ----------------
__global__ void k_softmax(const float* __restrict__ scores, float* __restrict__ attn)
{
  __shared__ float red[512];
  const int b = blockIdx.x, tid = threadIdx.x;
  float v = scores[b*Ss + tid];
  red[tid] = v; __syncthreads();
  for (int off=256; off>0; off>>=1){ if (tid<off) red[tid] = fmaxf(red[tid], red[tid+off]); __syncthreads(); }
  float mx = red[0]; __syncthreads();
  float e = __expf(v - mx);
  red[tid] = e; __syncthreads();
  for (int off=256; off>0; off>>=1){ if (tid<off) red[tid] += red[tid+off]; __syncthreads(); }
  attn[b*Ss + tid] = e / red[0];
}

// ---------------- ctx partial: bf16 enc, 4 row-chunks of 128, vectorized ----------------
__global__ void k_ctx_bf16(const short* __restrict__ encb, const float* __restrict__ attn,
                           float* __restrict__ ctxp)
{
  __shared__ float a[128];
  const int bid = blockIdx.x, b = bid>>2, ch = bid&3, tid = threadIdx.x;
  if (tid < 128) a[tid] = attn[b*Ss + ch*128 + tid];
  __syncthreads();
  const short* e0 = encb + (size_t)(b*Ss + ch*128)*TWOH + tid*8;
  float s[8] = {};
  for (int r=0; r<128; ++r){
    bf16x8 v = *(const bf16x8*)(e0 + (size_t)r*TWOH);
    float w = a[r];
    #pragma unroll
    for (int j=0;j<8;++j) s[j] += w * bf2f(v[j]);
  }
  float* o = ctxp + (size_t)ch*Bb*TWOH + (size_t)b*TWOH + tid*8;
  #pragma unroll
  for (int j=0;j<8;++j) o[j] = s[j];
}

__global__ void k_ctxfin(const float* __restrict__ ctxp, short* __restrict__ xb)
{
  const int g = blockIdx.x*256 + threadIdx.x;
  const int b = g >> 11, col = g & 2047;
  const int N = Bb*TWOH;
  float v = ctxp[g] + ctxp[N+g] + ctxp[2*N+g] + ctxp[3*N+g];
  xb[b*2560 + 512 + col] = f2bf(v);
}

// fallback (small ws): fp32 enc, writes xb directly
__global__ void k_ctx_f32(const float* __restrict__ enc, const float* __restrict__ attn,
                          short* __restrict__ xb)
{
  __shared__ float a[512];
  const int ch = blockIdx.x, b = blockIdx.y, tid = threadIdx.x;
  a[tid]     = attn[b*Ss + tid];
  a[tid+256] = attn[b*Ss + tid + 256];
  __syncthreads();
  const float* e0 = enc + (size_t)b*Ss*TWOH + ch*256 + tid;
  float s0=0.f, s1=0.f, s2=0.f, s3=0.f;
  for (int s=0; s<512; s+=4){
    s0 += a[s]   * e0[(size_t)(s  )*TWOH];
    s1 += a[s+1] * e0[(size_t)(s+1)*TWOH];
    s2 += a[s+2] * e0[(size_t)(s+2)*TWOH];
    s3 += a[s+3] * e0[(size_t)(s+3)*TWOH];
  }
  xb[b*2560 + 512 + ch*256 + tid] = f2bf(s0+s1+s2+s3);
}

// ---------------- GRU gates + h_new ----------------
__global__ void k_gates(const float* __restrict__ gx, const float* __restrict__ gh,
                        const float* __restrict__ b_ih, const float* __restrict__ b_hh,
                        const float* __restrict__ h, float* __restrict__ hnew_out,
                        short* __restrict__ hnewb)
{
  const int gid = blockIdx.x*256 + threadIdx.x;
  const int b = gid >> 10, j = gid & 1023;
  float xr = gx[b*3072 + j]        + b_ih[j];
  float xz = gx[b*3072 + 1024 + j] + b_ih[1024+j];
  float xn = gx[b*3072 + 2048 + j] + b_ih[2048+j];
  float hr = gh[b*3072 + j]        + b_hh[j];
  float hz = gh[b*3072 + 1024 + j] + b_hh[1024+j];
  float hn = gh[b*3072 + 2048 + j] + b_hh[2048+j];
  float r = 1.f/(1.f + __expf(-(xr+hr)));
  float z = 1.f/(1.f + __expf(-(xz+hz)));
  float n = tanhf(xn + r*hn);
  float hv = (1.f - z)*n + z*h[b*Hh + j];
  hnew_out[gid] = hv;
  hnewb[gid] = f2bf(hv);
}

extern "C" void kernel_launch(void* const* d_in, const int* in_sizes, int n_in,
                              void* d_out, int out_size, void* d_ws, size_t ws_size,
                              hipStream_t stream)
{
  const int*   dec   = (const int*)  d_in[0];
  const float* h     = (const float*)d_in[1];
  const float* enc   = (const float*)d_in[2];
  const float* emb   = (const float*)d_in[3];
  const float* W_ah  = (const float*)d_in[4];
  const float* b_ah  = (const float*)d_in[5];
  const float* W_ae  = (const float*)d_in[6];
  const float* b_ae  = (const float*)d_in[7];
  const float* wsc   = (const float*)d_in[8];
  const float* W_ih  = (const float*)d_in[9];
  const float* W_hh  = (const float*)d_in[10];
  const float* b_ih  = (const float*)d_in[11];
  const float* b_hh  = (const float*)d_in[12];
  const float* W_out = (const float*)d_in[13];
  const float* b_out = (const float*)d_in[14];
  float* out = (float*)d_out;
  float* hnew_out = out + (size_t)Bb*Vv;

  char* w = (char*)d_ws;
  float* scores = (float*)w;  w += (size_t)65536*4;    // zeroed (atomic target)
  float* ahb    = (float*)w;  w += (size_t)131072*4;   // zeroed
  float* ghb    = (float*)w;  w += (size_t)393216*4;   // zeroed
  float* gxb    = (float*)w;  w += (size_t)393216*4;   // zeroed
  size_t zero_bytes = (size_t)(w - (char*)d_ws);
  float* attn   = (float*)w;  w += (size_t)65536*4;
  short* waeb   = (short*)w;  w += (size_t)2097152*2;
  short* xb     = (short*)w;  w += (size_t)128*2560*2;
  short* hb     = (short*)w;  w += (size_t)131072*2;
  short* hnb    = (short*)w;  w += (size_t)131072*2;
  float* ctxp   = (float*)w;  w += (size_t)4*Bb*TWOH*4;
  short* encb   = (short*)w;  w += (size_t)65536*2048*2;
  const bool big = ((size_t)(w - (char*)d_ws) <= ws_size);

  hipMemsetAsync(d_ws, 0, zero_bytes, stream);
  k_prep<<<4096, 256, 0, stream>>>(W_ae, waeb, h, hb, dec, emb, xb);
  k_gemm128<0><<<dim3(32,2), 256, 0, stream>>>(hb, 1024, W_ah, W_hh, ahb, ghb, nullptr, 8);
  if (big)
    k_scores_mp<<<256, 512, 0, stream>>>(enc, encb, waeb, ahb, b_ah, b_ae, wsc, scores);
  else
    k_scores_f32<<<2048, 512, 0, stream>>>(enc, waeb, ahb, b_ah, b_ae, wsc, scores);
  k_softmax<<<128, 512, 0, stream>>>(scores, attn);
  if (big){
    k_ctx_bf16<<<512, 256, 0, stream>>>(encb, attn, ctxp);
    k_ctxfin<<<1024, 256, 0, stream>>>(ctxp, xb);
  } else {
    k_ctx_f32<<<dim3(8,128), 256, 0, stream>>>(enc, attn, xb);
  }
  k_gemm128<1><<<dim3(24,4), 256, 0, stream>>>(xb, 2560, W_ih, nullptr, gxb, nullptr, nullptr, 10);
  k_gates<<<512, 256, 0, stream>>>(gxb, ghb, b_ih, b_hh, h, hnew_out, hnb);
  k_gemm128<2><<<dim3(393,1), 256, 0, stream>>>(hnb, 1024, W_out, nullptr, out, nullptr, b_out, 16);
}

// Round 14
// 535.539 us; speedup vs baseline: 1.8097x; 1.1121x over previous
//
#include <hip/hip_runtime.h>
#include <hip/hip_bf16.h>

#define DEVI __device__ __forceinline__

typedef short bf16x8 __attribute__((ext_vector_type(8)));
typedef float f32x4  __attribute__((ext_vector_type(4)));

static constexpr int Bb   = 128;
static constexpr int Ss   = 512;
static constexpr int Hh   = 1024;
static constexpr int Ee   = 512;
static constexpr int Vv   = 50257;
static constexpr int TWOH = 2048;

DEVI short f2bf(float f){ __hip_bfloat16 h = __float2bfloat16(f); return *reinterpret_cast<short*>(&h); }
DEVI float bf2f(short s){ __hip_bfloat16 h = *reinterpret_cast<__hip_bfloat16*>(&s); return __bfloat162float(h); }

DEVI float tanh_fast(float x){            // 1 - 2/(e^2x + 1): ±inf-safe, ~1e-7 rel err
  float e = __expf(2.0f*x);
  return 1.0f - 2.0f/(e + 1.0f);
}

DEVI bf16x8 pack8(f32x4 a, f32x4 b){
  bf16x8 v;
  v[0]=f2bf(a[0]); v[1]=f2bf(a[1]); v[2]=f2bf(a[2]); v[3]=f2bf(a[3]);
  v[4]=f2bf(b[0]); v[5]=f2bf(b[1]); v[6]=f2bf(b[2]); v[7]=f2bf(b[3]);
  return v;
}

DEVI void gld_lds16(const void* g, void* l){
  __builtin_amdgcn_global_load_lds((const __attribute__((address_space(1))) void*)g,
                                   (__attribute__((address_space(3))) void*)l, 16, 0, 0);
}

DEVI f32x4 mfma16(bf16x8 a, bf16x8 b, f32x4 c){
  return __builtin_amdgcn_mfma_f32_16x16x32_bf16(a, b, c, 0, 0, 0);
}

// ---------------- prep: convert W_ae->bf16, h->bf16, gather emb into x_bf16 ----------------
__global__ void k_prep(const float* __restrict__ wae, short* __restrict__ waeb,
                       const float* __restrict__ h, short* __restrict__ hb,
                       const int* __restrict__ dec_in, const float* __restrict__ emb,
                       short* __restrict__ xb)
{
  const int total_wae = Hh*TWOH;
  const int total_h   = Bb*Hh;
  const int total_emb = Bb*Ee;
  const int total = total_wae + total_h + total_emb;
  for (int i = blockIdx.x*blockDim.x + threadIdx.x; i < total; i += gridDim.x*blockDim.x){
    if (i < total_wae) waeb[i] = f2bf(wae[i]);
    else if (i < total_wae + total_h){ int j = i - total_wae; hb[j] = f2bf(h[j]); }
    else {
      int j = i - total_wae - total_h;
      int b = j >> 9, e = j & 511;
      xb[b*2560 + e] = f2bf(emb[(size_t)dec_in[b]*Ee + e]);
    }
  }
}

// ---------------- scores GEMM, FUSED fp32->bf16, ISSUE-EARLY / COMMIT-LATE ------
// 256x256 tile, 8 waves (2M x 4N), BK=64, A+B double-buffered (128KB LDS).
// vs r10 (440us, MfmaUtil 26.7%): the A-prefetch had ~600cyc cover and hipcc
// could sink PREFA toward COMMITA. Fix (T14, G15): pin {STB(t+1); PREFA(t+1)}
// at tile top with sched_barrier(0); move COMMITA+STOREE to END of half2 (after
// all 64 MFMAs) -> full-tile (~1000cyc) cover. Ordering invariant: STB issued
// BEFORE PREFA, so COMMITA's pa-register vmcnt-wait retires STB(t+1) before the
// barrier releases waves into tile t+1 (in-order vmem retirement).
// nb==0 blocks persist converted regs to encb (linear copy) for k_ctx.
// XCD grouping: q&7 = XCD; 4 same-rt blocks share the fp32 A panel (2MB) in L2
// (r10-measured FETCH 328MB).
__launch_bounds__(512)
__global__ void k_scores_fuse(const float* __restrict__ enc, short* __restrict__ encb,
                              const short* __restrict__ waeb,
                              const float* __restrict__ ahb, const float* __restrict__ b_ah,
                              const float* __restrict__ b_ae, const float* __restrict__ wsc,
                              float* __restrict__ scores)
{
  __shared__ __align__(16) char LDSB[131072];   // A: 2x32KB @0, B: 2x32KB @65536
  const int q  = blockIdx.x;
  const int xcd = q & 7, sl = q >> 3;
  const int rt = xcd*32 + (sl>>2), nb = sl & 3; // rt 0..255, nb 0..3 (bijective)
  const int tid = threadIdx.x, wid = tid>>6, lane = tid&63;
  const int wr = wid>>2, wc = wid&3;            // 2M x 4N waves
  const int srow = lane>>3, l7 = lane&7;
  const int lo = lane&15, hi4 = lane>>4;
  const int swk = (l7 ^ srow)*8;                // pre-swizzled source k-chunk (elems)

  const float* Ag = enc  + (size_t)rt*256*TWOH + (size_t)(wid*8+srow)*TWOH + swk;
  const short* Bg = waeb + (size_t)nb*256*TWOH + (size_t)(wid*8+srow)*TWOH + swk;
  short*       Eg = encb + (size_t)rt*256*TWOH + (size_t)(wid*8+srow)*TWOH + swk;
  const bool we = (nb == 0) && (encb != nullptr);

  char* AWc = LDSB + wid*1024 + lane*16;        // + buf*32768 + rnd*8192 (ds_write)
  char* BW  = LDSB + 65536 + wid*1024;          // + buf*32768 + rnd*8192 (gld_lds, lane implicit)
  const char* AR = LDSB + (wr*128 + lo)*128;    // + buf*32768 + i*2048 + sw
  const char* BR = LDSB + 65536 + (wc*64 + lo)*128;
  const int sw0 = (hi4*16) ^ (l7<<4);           // kk=0 swizzled byte offset
  const int sw1 = (64 + hi4*16) ^ (l7<<4);      // kk=1

  f32x4 acc[8][4] = {};
  f32x4 pa[4][2];                               // pending fp32 A regs (one set)

  auto STB = [&](int buf, int kt){
    #pragma unroll
    for (int rnd=0; rnd<4; ++rnd)
      gld_lds16(Bg + (size_t)rnd*64*TWOH + kt*64, BW + buf*32768 + rnd*8192);
  };
  auto PREFA = [&](int kt){
    #pragma unroll
    for (int rnd=0; rnd<4; ++rnd){
      const float* p = Ag + (size_t)rnd*64*TWOH + kt*64;
      pa[rnd][0] = *(const f32x4*)p; pa[rnd][1] = *(const f32x4*)(p+4);
    }
  };
  auto COMMITA = [&](int buf){
    #pragma unroll
    for (int rnd=0; rnd<4; ++rnd)
      *(bf16x8*)(AWc + buf*32768 + rnd*8192) = pack8(pa[rnd][0], pa[rnd][1]);
  };
  auto STOREE = [&](int kt){
    #pragma unroll
    for (int rnd=0; rnd<4; ++rnd)
      *(bf16x8*)(Eg + (size_t)rnd*64*TWOH + kt*64) = pack8(pa[rnd][0], pa[rnd][1]);
  };

  // prologue: STB first (older), then PREFA(0)->commit (pa-wait retires STB(0)),
  // persist, prefetch A(1); drain ds_writes; barrier.
  STB(0,0);
  PREFA(0); COMMITA(0);
  if (we) STOREE(0);
  PREFA(1);
  asm volatile("s_waitcnt lgkmcnt(0)" ::: "memory");
  __builtin_amdgcn_s_barrier();
  __builtin_amdgcn_sched_barrier(0);

  for (int t = 0; t < 32; ++t){
    const int cur = t&1, nxt = cur^1;
    const int aO = cur*32768, bO = cur*32768;
    bf16x8 af[4], bq[4];

    // ---- issue-early (pinned): B(t+1) gld_lds THEN A(t+1) reg loads ----
    if (t<31){ STB(nxt, t+1); PREFA(t+1); }
    __builtin_amdgcn_sched_barrier(0);

    // ---- half 1 (kk0): 32 MFMA ----
    #pragma unroll
    for (int j=0;j<4;++j) bq[j] = *(const bf16x8*)(BR + bO + j*2048 + sw0);
    #pragma unroll
    for (int i=0;i<4;++i) af[i] = *(const bf16x8*)(AR + aO + i*2048 + sw0);
    __builtin_amdgcn_s_setprio(1);
    #pragma unroll
    for (int i=0;i<4;++i)
      #pragma unroll
      for (int j=0;j<4;++j)
        acc[i][j] = mfma16(af[i], bq[j], acc[i][j]);
    __builtin_amdgcn_s_setprio(0);
    #pragma unroll
    for (int i=0;i<4;++i) af[i] = *(const bf16x8*)(AR + aO + (4+i)*2048 + sw0);
    __builtin_amdgcn_s_setprio(1);
    #pragma unroll
    for (int i=0;i<4;++i)
      #pragma unroll
      for (int j=0;j<4;++j)
        acc[4+i][j] = mfma16(af[i], bq[j], acc[4+i][j]);
    __builtin_amdgcn_s_setprio(0);

    // ---- half 2 (kk1): 32 MFMA ----
    #pragma unroll
    for (int j=0;j<4;++j) bq[j] = *(const bf16x8*)(BR + bO + j*2048 + sw1);
    #pragma unroll
    for (int i=0;i<4;++i) af[i] = *(const bf16x8*)(AR + aO + i*2048 + sw1);
    __builtin_amdgcn_s_setprio(1);
    #pragma unroll
    for (int i=0;i<4;++i)
      #pragma unroll
      for (int j=0;j<4;++j)
        acc[i][j] = mfma16(af[i], bq[j], acc[i][j]);
    __builtin_amdgcn_s_setprio(0);
    #pragma unroll
    for (int i=0;i<4;++i) af[i] = *(const bf16x8*)(AR + aO + (4+i)*2048 + sw1);
    __builtin_amdgcn_s_setprio(1);
    #pragma unroll
    for (int i=0;i<4;++i)
      #pragma unroll
      for (int j=0;j<4;++j)
        acc[4+i][j] = mfma16(af[i], bq[j], acc[4+i][j]);
    __builtin_amdgcn_s_setprio(0);

    // ---- commit-late: pa-wait retires STB(t+1) (older); drain ds_writes; barrier ----
    __builtin_amdgcn_sched_barrier(0);
    if (t<31){
      COMMITA(nxt);
      if (we) STOREE(t+1);
    }
    asm volatile("s_waitcnt lgkmcnt(0)" ::: "memory");
    __builtin_amdgcn_s_barrier();
    __builtin_amdgcn_sched_barrier(0);
  }
  // epilogue: scores[m] += sum_n tanh(ah[b,n]+b_ah+b_ae+ae)*w_score[n]
  const int b = rt >> 1;                        // 256-row tile = half a batch row
  float w4[4], t4[4];
  #pragma unroll
  for (int j=0;j<4;++j){
    int n = nb*256 + wc*64 + j*16 + lo;
    w4[j] = wsc[n];
    t4[j] = ahb[b*Hh + n] + b_ah[n] + b_ae[n];
  }
  #pragma unroll
  for (int i=0;i<8;++i){
    #pragma unroll
    for (int q2=0;q2<4;++q2){
      int m = rt*256 + wr*128 + i*16 + hi4*4 + q2;
      float s = 0.f;
      #pragma unroll
      for (int j=0;j<4;++j) s += tanh_fast(t4[j] + acc[i][j][q2]) * w4[j];
      s += __shfl_xor(s,1); s += __shfl_xor(s,2); s += __shfl_xor(s,4); s += __shfl_xor(s,8);
      if (lo == 0) atomicAdd(&scores[m], s);
    }
  }
}

// ---------------- generic 128-row GEMM: A[128,K] bf16 ws, B[N,K] fp32 global --------------
template<int MODE>
__launch_bounds__(256)
__global__ void k_gemm128(const short* __restrict__ A, int lda,
                          const float* __restrict__ B0, const float* __restrict__ B1,
                          float* __restrict__ O0, float* __restrict__ O1,
                          const float* __restrict__ bias, int kiters)
{
  __shared__ __align__(16) short As[2][128*64];
  __shared__ __align__(16) short Bs[2][128*64];
  const int nb = blockIdx.x;
  const int tid = threadIdx.x, wid = tid>>6, lane = tid&63;
  const int wr = wid>>1, wc = wid&1;
  const int srow = lane>>3, l7 = lane&7;
  const int swk = (l7 ^ srow) * 8;

  const float* Bt; int noff; float* Ot; int ostride;
  if constexpr (MODE==0){
    if (nb < 8){ Bt = B0; noff = 0;    Ot = O0; ostride = Hh;   }
    else       { Bt = B1; noff = 1024; Ot = O1; ostride = 3*Hh; }
  } else if constexpr (MODE==1){ Bt = B0; noff = 0; Ot = O0; ostride = 3*Hh; }
  else { Bt = B0; noff = 0; Ot = O0; ostride = Vv; }

  f32x4 acc[4][4] = {};
  f32x4 pb0[4], pb1[4];

  auto stageA = [&](int s, int kt){
    #pragma unroll
    for (int i=0;i<4;++i){
      int c = wid*4+i, row = c*8+srow;
      gld_lds16(A + (size_t)row*lda + kt*64 + swk, (char*)As[s] + c*1024);
    }
  };
  auto prefB = [&](int kt){
    #pragma unroll
    for (int i=0;i<4;++i){
      int row = (wid*4+i)*8+srow;
      int n = nb*128 + row - noff;
      if constexpr (MODE==2) n = (n > Vv-1) ? (Vv-1) : n;
      const float* bp = Bt + (size_t)n*lda + kt*64 + l7*8;
      pb0[i] = *(const f32x4*)bp; pb1[i] = *(const f32x4*)(bp+4);
    }
  };
  auto commitB = [&](int s){
    #pragma unroll
    for (int i=0;i<4;++i){
      int row = (wid*4+i)*8+srow;
      *(bf16x8*)((char*)Bs[s] + row*128 + ((l7^srow)<<4)) = pack8(pb0[i], pb1[i]);
    }
  };

  const int kt0 = blockIdx.y * kiters, kend = kt0 + kiters;
  stageA(0, kt0); prefB(kt0); commitB(0);
  __syncthreads();

  int cur = 0;
  for (int kt = kt0; kt < kend; ++kt){
    if (kt+1 < kend){ stageA(cur^1, kt+1); prefB(kt+1); }
    #pragma unroll
    for (int kk=0;kk<2;++kk){
      bf16x8 af[4], bq[4];
      const int sw = (kk*64 + (lane>>4)*16) ^ (l7<<4);
      #pragma unroll
      for (int i=0;i<4;++i) af[i] = *(const bf16x8*)((const char*)As[cur] + (wr*64+i*16+(lane&15))*128 + sw);
      #pragma unroll
      for (int j=0;j<4;++j) bq[j] = *(const bf16x8*)((const char*)Bs[cur] + (wc*64+j*16+(lane&15))*128 + sw);
      #pragma unroll
      for (int i=0;i<4;++i)
        #pragma unroll
        for (int j=0;j<4;++j)
          acc[i][j] = mfma16(af[i], bq[j], acc[i][j]);
    }
    if (kt+1 < kend) commitB(cur^1);
    __syncthreads();
    cur ^= 1;
  }
  const int lo = lane&15, hi = lane>>4;
  #pragma unroll
  for (int i=0;i<4;++i){
    #pragma unroll
    for (int j=0;j<4;++j){
      int n = nb*128 + wc*64 + j*16 + lo - noff;
      #pragma unroll
      for (int q=0;q<4;++q){
        int m = wr*64 + i*16 + hi*4 + q;
        float v = acc[i][j][q];
        if constexpr (MODE==2){
          if (n < Vv) O0[(size_t)m*Vv + n] = v + bias[n];
        } else {
          atomicAdd(&Ot[(size_t)m*ostride + n], v);
        }
      }
    }
  }
}

// ---------------- softmax over S=512 per batch row ----------------
__global__ void k_softmax(const float* __restrict__ scores, float* __restrict__ attn)
{
  __shared__ float red[512];
  const int b = blockIdx.x, tid = threadIdx.x;
  float v = scores[b*Ss + tid];
  red[tid] = v; __syncthreads();
  for (int off=256; off>0; off>>=1){ if (tid<off) red[tid] = fmaxf(red[tid], red[tid+off]); __syncthreads(); }
  float mx = red[0]; __syncthreads();
  float e = __expf(v - mx);
  red[tid] = e; __syncthreads();
  for (int off=256; off>0; off>>=1){ if (tid<off) red[tid] += red[tid+off]; __syncthreads(); }
  attn[b*Ss + tid] = e / red[0];
}

// ---------------- ctx partial: bf16 enc, 4 row-chunks of 128, vectorized ----------------
__global__ void k_ctx_bf16(const short* __restrict__ encb, const float* __restrict__ attn,
                           float* __restrict__ ctxp)
{
  __shared__ float a[128];
  const int bid = blockIdx.x, b = bid>>2, ch = bid&3, tid = threadIdx.x;
  if (tid < 128) a[tid] = attn[b*Ss + ch*128 + tid];
  __syncthreads();
  const short* e0 = encb + (size_t)(b*Ss + ch*128)*TWOH + tid*8;
  float s[8] = {};
  for (int r=0; r<128; ++r){
    bf16x8 v = *(const bf16x8*)(e0 + (size_t)r*TWOH);
    float w = a[r];
    #pragma unroll
    for (int j=0;j<8;++j) s[j] += w * bf2f(v[j]);
  }
  float* o = ctxp + (size_t)ch*Bb*TWOH + (size_t)b*TWOH + tid*8;
  #pragma unroll
  for (int j=0;j<8;++j) o[j] = s[j];
}

__global__ void k_ctxfin(const float* __restrict__ ctxp, short* __restrict__ xb)
{
  const int g = blockIdx.x*256 + threadIdx.x;
  const int b = g >> 11, col = g & 2047;
  const int N = Bb*TWOH;
  float v = ctxp[g] + ctxp[N+g] + ctxp[2*N+g] + ctxp[3*N+g];
  xb[b*2560 + 512 + col] = f2bf(v);
}

// fallback (small ws): fp32 enc, writes xb directly
__global__ void k_ctx_f32(const float* __restrict__ enc, const float* __restrict__ attn,
                          short* __restrict__ xb)
{
  __shared__ float a[512];
  const int ch = blockIdx.x, b = blockIdx.y, tid = threadIdx.x;
  a[tid]     = attn[b*Ss + tid];
  a[tid+256] = attn[b*Ss + tid + 256];
  __syncthreads();
  const float* e0 = enc + (size_t)b*Ss*TWOH + ch*256 + tid;
  float s0=0.f, s1=0.f, s2=0.f, s3=0.f;
  for (int s=0; s<512; s+=4){
    s0 += a[s]   * e0[(size_t)(s  )*TWOH];
    s1 += a[s+1] * e0[(size_t)(s+1)*TWOH];
    s2 += a[s+2] * e0[(size_t)(s+2)*TWOH];
    s3 += a[s+3] * e0[(size_t)(s+3)*TWOH];
  }
  xb[b*2560 + 512 + ch*256 + tid] = f2bf(s0+s1+s2+s3);
}

// ---------------- GRU gates + h_new ----------------
__global__ void k_gates(const float* __restrict__ gx, const float* __restrict__ gh,
                        const float* __restrict__ b_ih, const float* __restrict__ b_hh,
                        const float* __restrict__ h, float* __restrict__ hnew_out,
                        short* __restrict__ hnewb)
{
  const int gid = blockIdx.x*256 + threadIdx.x;
  const int b = gid >> 10, j = gid & 1023;
  float xr = gx[b*3072 + j]        + b_ih[j];
  float xz = gx[b*3072 + 1024 + j] + b_ih[1024+j];
  float xn = gx[b*3072 + 2048 + j] + b_ih[2048+j];
  float hr = gh[b*3072 + j]        + b_hh[j];
  float hz = gh[b*3072 + 1024 + j] + b_hh[1024+j];
  float hn = gh[b*3072 + 2048 + j] + b_hh[2048+j];
  float r = 1.f/(1.f + __expf(-(xr+hr)));
  float z = 1.f/(1.f + __expf(-(xz+hz)));
  float n = tanhf(xn + r*hn);
  float hv = (1.f - z)*n + z*h[b*Hh + j];
  hnew_out[gid] = hv;
  hnewb[gid] = f2bf(hv);
}

extern "C" void kernel_launch(void* const* d_in, const int* in_sizes, int n_in,
                              void* d_out, int out_size, void* d_ws, size_t ws_size,
                              hipStream_t stream)
{
  const int*   dec   = (const int*)  d_in[0];
  const float* h     = (const float*)d_in[1];
  const float* enc   = (const float*)d_in[2];
  const float* emb   = (const float*)d_in[3];
  const float* W_ah  = (const float*)d_in[4];
  const float* b_ah  = (const float*)d_in[5];
  const float* W_ae  = (const float*)d_in[6];
  const float* b_ae  = (const float*)d_in[7];
  const float* wsc   = (const float*)d_in[8];
  const float* W_ih  = (const float*)d_in[9];
  const float* W_hh  = (const float*)d_in[10];
  const float* b_ih  = (const float*)d_in[11];
  const float* b_hh  = (const float*)d_in[12];
  const float* W_out = (const float*)d_in[13];
  const float* b_out = (const float*)d_in[14];
  float* out = (float*)d_out;
  float* hnew_out = out + (size_t)Bb*Vv;

  char* w = (char*)d_ws;
  float* scores = (float*)w;  w += (size_t)65536*4;    // zeroed (atomic target)
  float* ahb    = (float*)w;  w += (size_t)131072*4;   // zeroed
  float* ghb    = (float*)w;  w += (size_t)393216*4;   // zeroed
  float* gxb    = (float*)w;  w += (size_t)393216*4;   // zeroed
  size_t zero_bytes = (size_t)(w - (char*)d_ws);
  float* attn   = (float*)w;  w += (size_t)65536*4;
  short* waeb   = (short*)w;  w += (size_t)2097152*2;
  short* xb     = (short*)w;  w += (size_t)128*2560*2;
  short* hb     = (short*)w;  w += (size_t)131072*2;
  short* hnb    = (short*)w;  w += (size_t)131072*2;
  float* ctxp   = (float*)w;  w += (size_t)4*Bb*TWOH*4;
  short* encb   = (short*)w;  w += (size_t)65536*2048*2;
  const bool big = ((size_t)(w - (char*)d_ws) <= ws_size);

  hipMemsetAsync(d_ws, 0, zero_bytes, stream);
  k_prep<<<4096, 256, 0, stream>>>(W_ae, waeb, h, hb, dec, emb, xb);
  k_gemm128<0><<<dim3(32,2), 256, 0, stream>>>(hb, 1024, W_ah, W_hh, ahb, ghb, nullptr, 8);
  k_scores_fuse<<<1024, 512, 0, stream>>>(enc, big ? encb : nullptr, waeb,
                                          ahb, b_ah, b_ae, wsc, scores);
  k_softmax<<<128, 512, 0, stream>>>(scores, attn);
  if (big){
    k_ctx_bf16<<<512, 256, 0, stream>>>(encb, attn, ctxp);
    k_ctxfin<<<1024, 256, 0, stream>>>(ctxp, xb);
  } else {
    k_ctx_f32<<<dim3(8,128), 256, 0, stream>>>(enc, attn, xb);
  }
  k_gemm128<1><<<dim3(24,4), 256, 0, stream>>>(xb, 2560, W_ih, nullptr, gxb, nullptr, nullptr, 10);
  k_gates<<<512, 256, 0, stream>>>(gxb, ghb, b_ih, b_hh, h, hnew_out, hnb);
  k_gemm128<2><<<dim3(393,1), 256, 0, stream>>>(hnb, 1024, W_out, nullptr, out, nullptr, b_out, 16);
}